// Round 3
// baseline (528.590 us; speedup 1.0000x reference)
//
#include <hip/hip_runtime.h>
#include <math.h>

// ---------------------------------------------------------------------------
// GAT 2-layer forward (N=50000, F_in=256, H1=8, C1=32, C2=32, E=500000).
// Strategy: build CSR-by-dst once (degree->scan->scatter), then per-dst-node
// blocks do online-softmax attention aggregation (no float atomics).
// All fp32 (no fp32 MFMA on CDNA4; GEMMs on vector ALU).
// ---------------------------------------------------------------------------

__global__ void zero_kernel(int* p, int n) {
    int i = blockIdx.x * blockDim.x + threadIdx.x;
    if (i < n) p[i] = 0;
}

// Decide whether edge_index arrived as int32 or int64.
// int64 little-endian values < 2^31 => every odd 32-bit word is 0.
__global__ void detect_kernel(const int* ei32, int* flag) {
    __shared__ int cnt;
    if (threadIdx.x == 0) cnt = 0;
    __syncthreads();
    int nz = 0;
    for (int i = threadIdx.x; i < 1024; i += blockDim.x)
        if (ei32[2 * i + 1] != 0) nz++;
    atomicAdd(&cnt, nz);
    __syncthreads();
    if (threadIdx.x == 0) *flag = (cnt > 16) ? 1 : 0;  // 1 => int32 layout
}

// Decode edges (+ appended self-loops), count in-degree per dst.
__global__ void decode_degree_kernel(const void* ei, int E, int ET, int N,
                                     const int* __restrict__ flag,
                                     int* __restrict__ src, int* __restrict__ dst,
                                     int* __restrict__ deg) {
    int k = blockIdx.x * blockDim.x + threadIdx.x;
    if (k >= ET) return;
    int s, d;
    if (k < E) {
        if (*flag) {
            const int* p = (const int*)ei;
            s = p[k]; d = p[E + k];
        } else {
            const long long* p = (const long long*)ei;
            s = (int)p[k]; d = (int)p[E + k];
        }
    } else {  // self-loop edges appended after real edges
        s = d = k - E;
    }
    s = min(max(s, 0), N - 1);
    d = min(max(d, 0), N - 1);
    src[k] = s; dst[k] = d;
    atomicAdd(&deg[d], 1);
}

// Exclusive prefix sum over deg[0..n) -> off[0..n], single block of 1024.
__global__ __launch_bounds__(1024) void scan_kernel(const int* __restrict__ deg,
                                                    int* __restrict__ off, int n) {
    __shared__ int sm[1024];
    __shared__ int carry;
    int t = threadIdx.x;
    if (t == 0) { carry = 0; off[0] = 0; }
    __syncthreads();
    for (int base = 0; base < n; base += 1024) {
        int v = (base + t < n) ? deg[base + t] : 0;
        sm[t] = v;
        __syncthreads();
        for (int s = 1; s < 1024; s <<= 1) {
            int a = (t >= s) ? sm[t - s] : 0;
            __syncthreads();
            sm[t] += a;
            __syncthreads();
        }
        int inc = sm[t];          // inclusive scan within chunk
        int c = carry;
        if (base + t < n) off[base + t + 1] = c + inc;
        __syncthreads();
        if (t == 1023) carry = c + sm[1023];
        __syncthreads();
    }
}

// Scatter src ids into CSR slots per dst.
__global__ void scatter_kernel(const int* __restrict__ src, const int* __restrict__ dst,
                               int ET, const int* __restrict__ off,
                               int* __restrict__ cursor, int* __restrict__ esrc) {
    int k = blockIdx.x * blockDim.x + threadIdx.x;
    if (k >= ET) return;
    int d = dst[k];
    int p = atomicAdd(&cursor[d], 1);
    esrc[off[d] + p] = src[k];
}

// h1 = x @ W1  ([N,256]@[256,256]); also alpha_s1/alpha_d1 per (node, head).
// Block: 256 threads = 256 output cols; 32 rows per block staged in LDS.
__global__ __launch_bounds__(256) void gemm1_kernel(
        const float* __restrict__ x, const float* __restrict__ W1,
        const float* __restrict__ a_src1, const float* __restrict__ a_dst1,
        float* __restrict__ h1, float* __restrict__ as1, float* __restrict__ ad1, int N) {
    __shared__ float xs[32][256];   // 32 KB
    int t = threadIdx.x;
    int row0 = blockIdx.x * 32;
    for (int i = t; i < 32 * 256; i += 256) {
        int r = i >> 8, c = i & 255;
        int gr = row0 + r;
        xs[r][c] = (gr < N) ? x[(size_t)gr * 256 + c] : 0.f;
    }
    __syncthreads();
    int col = t;
    float acc[32];
#pragma unroll
    for (int r = 0; r < 32; r++) acc[r] = 0.f;
    for (int k = 0; k < 256; k += 4) {
        float w0 = W1[(k + 0) * 256 + col];
        float w1 = W1[(k + 1) * 256 + col];
        float w2 = W1[(k + 2) * 256 + col];
        float w3 = W1[(k + 3) * 256 + col];
#pragma unroll
        for (int r = 0; r < 32; r++) {
            float4 xv = *reinterpret_cast<const float4*>(&xs[r][k]);
            float a = acc[r];
            a = fmaf(xv.x, w0, a);
            a = fmaf(xv.y, w1, a);
            a = fmaf(xv.z, w2, a);
            a = fmaf(xv.w, w3, a);
            acc[r] = a;
        }
    }
    int head = col >> 5;
    float asv = a_src1[col];   // a_src1 is [8][32] flat = [256]
    float adv = a_dst1[col];
#pragma unroll 1
    for (int r = 0; r < 32; r++) {
        int gr = row0 + r;
        if (gr < N) h1[(size_t)gr * 256 + col] = acc[r];
        float vs = acc[r] * asv;
        float vd = acc[r] * adv;
#pragma unroll
        for (int s = 16; s > 0; s >>= 1) {
            vs += __shfl_down(vs, s, 32);
            vd += __shfl_down(vd, s, 32);
        }
        if ((col & 31) == 0 && gr < N) {
            as1[gr * 8 + head] = vs;
            ad1[gr * 8 + head] = vd;
        }
    }
}

// Layer-1 attention aggregation. One block (256 thr = 8 heads x 32 ch) per dst
// node. Online softmax over incoming edges, 32-edge chunks; coalesced 1KB
// gather of h1[src] per edge. Fuses +b1 and elu -> hact.
__global__ __launch_bounds__(256) void agg1_kernel(
        const float* __restrict__ h1,
        const float* __restrict__ as1, const float* __restrict__ ad1,
        const float* __restrict__ b1,
        const int* __restrict__ off, const int* __restrict__ esrc,
        float* __restrict__ hact, int N) {
    int node = blockIdx.x;
    int t = threadIdx.x;
    int head = t >> 5;
    int beg = off[node], end = off[node + 1];
    __shared__ int s_src[32];
    __shared__ float s_e[32][8];
    float adv = ad1[node * 8 + head];
    float m = -3.0e38f, dnm = 0.f, acc = 0.f;
    for (int base = beg; base < end; base += 32) {
        int n_ch = min(32, end - base);
        __syncthreads();                     // protect LDS from previous chunk
        if (t < 32) s_src[t] = (t < n_ch) ? esrc[base + t] : 0;
        __syncthreads();
        {
            int j = t & 31;                  // thread (j, head) computes e[j][head]
            if (j < n_ch) {
                int s = s_src[j];
                float e = as1[s * 8 + head] + adv;
                s_e[j][head] = (e > 0.f) ? e : 0.2f * e;   // leaky_relu(0.2)
            }
        }
        __syncthreads();
        float cm = -3.0e38f;
        for (int j = 0; j < n_ch; j++) cm = fmaxf(cm, s_e[j][head]);
        float nm = fmaxf(m, cm);
        float scl = __expf(m - nm);          // exp(-inf)=0 on first chunk
        dnm *= scl; acc *= scl;
        for (int j = 0; j < n_ch; j++) {
            float w = __expf(s_e[j][head] - nm);
            int s = s_src[j];
            acc = fmaf(w, h1[(size_t)s * 256 + t], acc);   // coalesced 1KB/edge
            dnm += w;
        }
        m = nm;
    }
    float out = acc / (dnm + 1e-16f) + b1[t];
    hact[(size_t)node * 256 + t] = (out > 0.f) ? out : (__expf(out) - 1.f);  // elu
}

// h2 = hact @ W2 ([N,256]@[256,32]); also alpha_s2/alpha_d2 per node.
// Block: 256 threads = 8 nodes x 32 cols.
__global__ __launch_bounds__(256) void gemm2_kernel(
        const float* __restrict__ hact, const float* __restrict__ W2,
        const float* __restrict__ a_src2, const float* __restrict__ a_dst2,
        float* __restrict__ h2, float* __restrict__ as2, float* __restrict__ ad2, int N) {
    __shared__ float xs[8][256];
    int t = threadIdx.x;
    int node0 = blockIdx.x * 8;
    for (int i = t; i < 8 * 256; i += 256) {
        int r = i >> 8, c = i & 255;
        int gn = node0 + r;
        xs[r][c] = (gn < N) ? hact[(size_t)gn * 256 + c] : 0.f;
    }
    __syncthreads();
    int r = t >> 5, c = t & 31;
    float acc = 0.f;
    for (int k = 0; k < 256; k += 4) {
        float4 xv = *reinterpret_cast<const float4*>(&xs[r][k]);
        acc = fmaf(xv.x, W2[(k + 0) * 32 + c], acc);
        acc = fmaf(xv.y, W2[(k + 1) * 32 + c], acc);
        acc = fmaf(xv.z, W2[(k + 2) * 32 + c], acc);
        acc = fmaf(xv.w, W2[(k + 3) * 32 + c], acc);
    }
    int gn = node0 + r;
    if (gn < N) {
        h2[(size_t)gn * 32 + c] = acc;
        float vs = acc * a_src2[c];
        float vd = acc * a_dst2[c];
#pragma unroll
        for (int s = 16; s > 0; s >>= 1) {
            vs += __shfl_down(vs, s, 32);
            vd += __shfl_down(vd, s, 32);
        }
        if (c == 0) { as2[gn] = vs; ad2[gn] = vd; }
    }
}

// Layer-2 aggregation + bias + log_softmax, fused. 32-lane group per node.
__global__ __launch_bounds__(256) void agg2_kernel(
        const float* __restrict__ h2,
        const float* __restrict__ as2, const float* __restrict__ ad2,
        const float* __restrict__ b2,
        const int* __restrict__ off, const int* __restrict__ esrc,
        float* __restrict__ out, int N) {
    int t = threadIdx.x;
    int g = t >> 5, c = t & 31;
    int node = blockIdx.x * 8 + g;
    if (node >= N) return;
    int beg = off[node], end = off[node + 1];
    float adv = ad2[node];
    float m = -3.0e38f, dnm = 0.f, acc = 0.f;
    for (int j = beg; j < end; j++) {
        int s = esrc[j];
        float e = as2[s] + adv;
        e = (e > 0.f) ? e : 0.2f * e;
        float nm = fmaxf(m, e);
        float scl = __expf(m - nm);
        float w = __expf(e - nm);
        dnm = dnm * scl + w;
        acc = acc * scl + w * h2[(size_t)s * 32 + c];  // 128B coalesced / group
        m = nm;
    }
    float v = acc / (dnm + 1e-16f) + b2[c];
    // log_softmax over the 32 channels (one 32-lane group)
    float mx = v;
#pragma unroll
    for (int s = 16; s > 0; s >>= 1) mx = fmaxf(mx, __shfl_xor(mx, s, 32));
    float sum = __expf(v - mx);
#pragma unroll
    for (int s = 16; s > 0; s >>= 1) sum += __shfl_xor(sum, s, 32);
    out[(size_t)node * 32 + c] = (v - mx) - __logf(sum);
}

extern "C" void kernel_launch(void* const* d_in, const int* in_sizes, int n_in,
                              void* d_out, int out_size, void* d_ws, size_t ws_size,
                              hipStream_t stream) {
    const float* x      = (const float*)d_in[0];
    const void*  ei     = d_in[1];
    const float* W1     = (const float*)d_in[2];
    const float* a_src1 = (const float*)d_in[3];
    const float* a_dst1 = (const float*)d_in[4];
    const float* b1     = (const float*)d_in[5];
    const float* W2     = (const float*)d_in[6];
    const float* a_src2 = (const float*)d_in[7];
    const float* a_dst2 = (const float*)d_in[8];
    const float* b2     = (const float*)d_in[9];
    const int N  = in_sizes[0] / 256;   // 50000
    const int E  = in_sizes[1] / 2;     // 500000
    const int ET = E + N;               // + self loops
    float* outp = (float*)d_out;
    (void)n_in; (void)out_size; (void)ws_size;

    // workspace layout (~120 MB total)
    char* ws = (char*)d_ws;
    size_t o = 0;
    auto alloc = [&](size_t bytes) -> void* {
        void* p = ws + o;
        o += (bytes + 255) & ~(size_t)255;
        return p;
    };
    int*   flag   = (int*)alloc(4);
    int*   src32  = (int*)alloc((size_t)ET * 4);
    int*   dst32  = (int*)alloc((size_t)ET * 4);
    int*   deg    = (int*)alloc((size_t)2 * N * 4);  // deg + cursor
    int*   cursor = deg + N;
    int*   off    = (int*)alloc((size_t)(N + 1) * 4);
    int*   esrc   = (int*)alloc((size_t)ET * 4);
    float* h1     = (float*)alloc((size_t)N * 256 * 4);
    float* as1    = (float*)alloc((size_t)N * 8 * 4);
    float* ad1    = (float*)alloc((size_t)N * 8 * 4);
    float* hact   = (float*)alloc((size_t)N * 256 * 4);
    float* h2     = (float*)alloc((size_t)N * 32 * 4);
    float* as2    = (float*)alloc((size_t)N * 4);
    float* ad2    = (float*)alloc((size_t)N * 4);

    zero_kernel<<<(2 * N + 255) / 256, 256, 0, stream>>>(deg, 2 * N);
    detect_kernel<<<1, 256, 0, stream>>>((const int*)ei, flag);
    decode_degree_kernel<<<(ET + 255) / 256, 256, 0, stream>>>(ei, E, ET, N, flag,
                                                               src32, dst32, deg);
    scan_kernel<<<1, 1024, 0, stream>>>(deg, off, N);
    scatter_kernel<<<(ET + 255) / 256, 256, 0, stream>>>(src32, dst32, ET, off,
                                                         cursor, esrc);
    gemm1_kernel<<<(N + 31) / 32, 256, 0, stream>>>(x, W1, a_src1, a_dst1,
                                                    h1, as1, ad1, N);
    agg1_kernel<<<N, 256, 0, stream>>>(h1, as1, ad1, b1, off, esrc, hact, N);
    gemm2_kernel<<<(N + 7) / 8, 256, 0, stream>>>(hact, W2, a_src2, a_dst2,
                                                  h2, as2, ad2, N);
    agg2_kernel<<<(N + 7) / 8, 256, 0, stream>>>(h2, as2, ad2, b2, off, esrc,
                                                 outp, N);
}

// Round 4
// 379.051 us; speedup vs baseline: 1.3945x; 1.3945x over previous
//
#include <hip/hip_runtime.h>
#include <math.h>

// ---------------------------------------------------------------------------
// GAT 2-layer forward (N=50000, F_in=256, H1=8, C1=32, C2=32, E=500000).
// R3: GEMM1 -> bf16 MFMA (16x16x32, fp32 accum); h1 stored bf16 (halves agg1
// gather); single-block scan rewritten (20 barriers instead of ~980).
// Attention softmax math stays fp32. CSR build unchanged.
// ---------------------------------------------------------------------------

typedef __attribute__((ext_vector_type(8))) short bf16x8;
typedef __attribute__((ext_vector_type(4))) float f32x4;

__device__ __forceinline__ float bf2f(ushort u) {
    union { uint i; float f; } v; v.i = ((uint)u) << 16; return v.f;
}
__device__ __forceinline__ ushort f2bf(float f) {  // round-to-nearest-even
    union { float f; uint i; } v; v.f = f;
    uint r = v.i + 0x7FFFu + ((v.i >> 16) & 1u);
    return (ushort)(r >> 16);
}

__global__ void zero_kernel(int* p, int n) {
    int i = blockIdx.x * blockDim.x + threadIdx.x;
    if (i < n) p[i] = 0;
}

// int64 little-endian values < 2^31 => every odd 32-bit word is 0.
__global__ void detect_kernel(const int* ei32, int* flag) {
    __shared__ int cnt;
    if (threadIdx.x == 0) cnt = 0;
    __syncthreads();
    int nz = 0;
    for (int i = threadIdx.x; i < 1024; i += blockDim.x)
        if (ei32[2 * i + 1] != 0) nz++;
    atomicAdd(&cnt, nz);
    __syncthreads();
    if (threadIdx.x == 0) *flag = (cnt > 16) ? 1 : 0;  // 1 => int32 layout
}

__global__ void decode_degree_kernel(const void* ei, int E, int ET, int N,
                                     const int* __restrict__ flag,
                                     int* __restrict__ src, int* __restrict__ dst,
                                     int* __restrict__ deg) {
    int k = blockIdx.x * blockDim.x + threadIdx.x;
    if (k >= ET) return;
    int s, d;
    if (k < E) {
        if (*flag) {
            const int* p = (const int*)ei;
            s = p[k]; d = p[E + k];
        } else {
            const long long* p = (const long long*)ei;
            s = (int)p[k]; d = (int)p[E + k];
        }
    } else {
        s = d = k - E;  // self-loops appended
    }
    s = min(max(s, 0), N - 1);
    d = min(max(d, 0), N - 1);
    src[k] = s; dst[k] = d;
    atomicAdd(&deg[d], 1);
}

// Exclusive prefix sum: each thread serially sums a 49-element chunk, one
// 1024-wide Hillis-Steele over partials (20 barriers total), serial writeback.
__global__ __launch_bounds__(1024) void scan_kernel(const int* __restrict__ deg,
                                                    int* __restrict__ off, int n) {
    __shared__ int partial[1024];
    int t = threadIdx.x;
    int per = (n + 1023) / 1024;
    int b0 = t * per;
    int e0 = min(b0 + per, n);
    int s = 0;
    for (int i = b0; i < e0; i++) s += deg[i];
    partial[t] = s;
    __syncthreads();
    for (int st = 1; st < 1024; st <<= 1) {
        int v = (t >= st) ? partial[t - st] : 0;
        __syncthreads();
        partial[t] += v;
        __syncthreads();
    }
    int run = partial[t] - s;   // exclusive prefix of this thread's chunk
    if (t == 0) off[0] = 0;
    for (int i = b0; i < e0; i++) { run += deg[i]; off[i + 1] = run; }
}

__global__ void scatter_kernel(const int* __restrict__ src, const int* __restrict__ dst,
                               int ET, const int* __restrict__ off,
                               int* __restrict__ cursor, int* __restrict__ esrc) {
    int k = blockIdx.x * blockDim.x + threadIdx.x;
    if (k >= ET) return;
    int d = dst[k];
    int p = atomicAdd(&cursor[d], 1);
    esrc[off[d] + p] = src[k];
}

// x fp32 -> bf16, 8 elems/thread.
__global__ void convert_x(const float* __restrict__ x, ushort* __restrict__ xb, long n) {
    long i = ((long)blockIdx.x * blockDim.x + threadIdx.x) * 8;
    if (i >= n) return;
    float4 a = *(const float4*)&x[i];
    float4 b = *(const float4*)&x[i + 4];
    uint4 o;
    o.x = (uint)f2bf(a.x) | ((uint)f2bf(a.y) << 16);
    o.y = (uint)f2bf(a.z) | ((uint)f2bf(a.w) << 16);
    o.z = (uint)f2bf(b.x) | ((uint)f2bf(b.y) << 16);
    o.w = (uint)f2bf(b.z) | ((uint)f2bf(b.w) << 16);
    *(uint4*)&xb[i] = o;
}

// W1[256][256] fp32 -> w1t[256][256] bf16 transposed (w1t[n][k] = W1[k][n]).
__global__ __launch_bounds__(256) void convert_w1t(const float* __restrict__ W1,
                                                   ushort* __restrict__ w1t) {
    __shared__ float tile[32][33];
    int tx = threadIdx.x & 31, ty = threadIdx.x >> 5;
    int bx = blockIdx.x, by = blockIdx.y;
    for (int i = 0; i < 32; i += 8)
        tile[ty + i][tx] = W1[(by * 32 + ty + i) * 256 + bx * 32 + tx];
    __syncthreads();
    for (int i = 0; i < 32; i += 8)
        w1t[(bx * 32 + ty + i) * 256 + by * 32 + tx] = f2bf(tile[tx][ty + i]);
}

// h1 = x @ W1 via bf16 MFMA. Block tile 128x128, BK=64, 4 waves (2x2), each
// wave a 64x64 sub-tile = 4x4 fragments of 16x16x32. Padded LDS rows (72 bf16)
// keep ds_read_b128/ds_write_b128 at the structural minimum (no conflicts).
#define LDA 72
__global__ __launch_bounds__(256) void gemm1_mfma(
        const ushort* __restrict__ xb,    // [N][256] bf16
        const ushort* __restrict__ w1t,   // [256][256] bf16 (n-major)
        ushort* __restrict__ h1b,         // [N][256] bf16 out
        int N) {
    __shared__ ushort Al[128 * LDA];
    __shared__ ushort Bl[128 * LDA];
    int t = threadIdx.x;
    int row0 = blockIdx.x * 128;
    int n0 = blockIdx.y * 128;
    int lane = t & 63, wid = t >> 6;
    int wr = wid >> 1, wc = wid & 1;

    f32x4 acc[4][4] = {};

    int sr = t >> 1, scs = (t & 1) * 32;   // staging: row, col-segment
    for (int k0 = 0; k0 < 256; k0 += 64) {
        // stage A tile (128 x 64) with bounds guard
        {
            int gr = row0 + sr;
            uint4 v0 = {0,0,0,0}, v1 = {0,0,0,0}, v2 = {0,0,0,0}, v3 = {0,0,0,0};
            if (gr < N) {
                const uint4* g = (const uint4*)(xb + (size_t)gr * 256 + k0 + scs);
                v0 = g[0]; v1 = g[1]; v2 = g[2]; v3 = g[3];
            }
            uint4* d = (uint4*)&Al[sr * LDA + scs];
            d[0] = v0; d[1] = v1; d[2] = v2; d[3] = v3;
        }
        // stage B tile (128 n-rows x 64 k) from pre-transposed w1t
        {
            const uint4* g = (const uint4*)(w1t + (size_t)(n0 + sr) * 256 + k0 + scs);
            uint4* d = (uint4*)&Bl[sr * LDA + scs];
            d[0] = g[0]; d[1] = g[1]; d[2] = g[2]; d[3] = g[3];
        }
        __syncthreads();

#pragma unroll
        for (int ks = 0; ks < 2; ks++) {
            int kk = ks * 32 + (lane >> 4) * 8;
            bf16x8 af[4], bfr[4];
#pragma unroll
            for (int mi = 0; mi < 4; mi++) {
                int r = wr * 64 + mi * 16 + (lane & 15);
                af[mi] = *(const bf16x8*)&Al[r * LDA + kk];
            }
#pragma unroll
            for (int ni = 0; ni < 4; ni++) {
                int r = wc * 64 + ni * 16 + (lane & 15);
                bfr[ni] = *(const bf16x8*)&Bl[r * LDA + kk];
            }
#pragma unroll
            for (int mi = 0; mi < 4; mi++)
#pragma unroll
                for (int ni = 0; ni < 4; ni++)
                    acc[mi][ni] = __builtin_amdgcn_mfma_f32_16x16x32_bf16(
                        af[mi], bfr[ni], acc[mi][ni], 0, 0, 0);
        }
        __syncthreads();
    }

    // C/D layout (m89/m91): col = lane&15, row = (lane>>4)*4 + j
#pragma unroll
    for (int mi = 0; mi < 4; mi++)
#pragma unroll
        for (int ni = 0; ni < 4; ni++) {
            int gc = n0 + wc * 64 + ni * 16 + (lane & 15);
#pragma unroll
            for (int j = 0; j < 4; j++) {
                int gr = row0 + wr * 64 + mi * 16 + (lane >> 4) * 4 + j;
                if (gr < N) h1b[(size_t)gr * 256 + gc] = f2bf(acc[mi][ni][j]);
            }
        }
}

// as1/ad1 per (node, head) from bf16 h1. 32-lane group per node.
__global__ __launch_bounds__(256) void alpha1_kernel(
        const ushort* __restrict__ h1b,
        const float* __restrict__ a_src1, const float* __restrict__ a_dst1,
        float* __restrict__ as1, float* __restrict__ ad1, int N) {
    int t = threadIdx.x;
    int g = t >> 5, l = t & 31;
    int node = blockIdx.x * 8 + g;
    if (node >= N) return;
    bf16x8 hv = *(const bf16x8*)&h1b[(size_t)node * 256 + l * 8];
    float s = 0.f, d = 0.f;
#pragma unroll
    for (int i = 0; i < 8; i++) {
        float h = bf2f((ushort)hv[i]);
        s = fmaf(h, a_src1[l * 8 + i], s);
        d = fmaf(h, a_dst1[l * 8 + i], d);
    }
    // head = l>>2 (each head = 32 cols = 4 lanes x 8)
    s += __shfl_xor(s, 1); s += __shfl_xor(s, 2);
    d += __shfl_xor(d, 1); d += __shfl_xor(d, 2);
    if ((l & 3) == 0) {
        as1[node * 8 + (l >> 2)] = s;
        ad1[node * 8 + (l >> 2)] = d;
    }
}

// Layer-1 aggregation: one block (8 heads x 32 ch) per dst node, online
// softmax, bf16 gathers of h1[src] (512B/edge). Fuses +b1 and elu.
__global__ __launch_bounds__(256) void agg1_kernel(
        const ushort* __restrict__ h1b,
        const float* __restrict__ as1, const float* __restrict__ ad1,
        const float* __restrict__ b1,
        const int* __restrict__ off, const int* __restrict__ esrc,
        float* __restrict__ hact, int N) {
    int node = blockIdx.x;
    int t = threadIdx.x;
    int head = t >> 5;
    int beg = off[node], end = off[node + 1];
    __shared__ int s_src[32];
    __shared__ float s_e[32][8];
    float adv = ad1[node * 8 + head];
    float m = -3.0e38f, dnm = 0.f, acc = 0.f;
    for (int base = beg; base < end; base += 32) {
        int n_ch = min(32, end - base);
        __syncthreads();
        if (t < 32) s_src[t] = (t < n_ch) ? esrc[base + t] : 0;
        __syncthreads();
        {
            int j = t & 31;
            if (j < n_ch) {
                int s = s_src[j];
                float e = as1[s * 8 + head] + adv;
                s_e[j][head] = (e > 0.f) ? e : 0.2f * e;
            }
        }
        __syncthreads();
        float cm = -3.0e38f;
        for (int j = 0; j < n_ch; j++) cm = fmaxf(cm, s_e[j][head]);
        float nm = fmaxf(m, cm);
        float scl = __expf(m - nm);
        dnm *= scl; acc *= scl;
        for (int j = 0; j < n_ch; j++) {
            float w = __expf(s_e[j][head] - nm);
            int s = s_src[j];
            acc = fmaf(w, bf2f(h1b[(size_t)s * 256 + t]), acc);
            dnm += w;
        }
        m = nm;
    }
    float out = acc / (dnm + 1e-16f) + b1[t];
    hact[(size_t)node * 256 + t] = (out > 0.f) ? out : (__expf(out) - 1.f);
}

// h2 = hact @ W2 ([N,256]@[256,32]) + alpha2. fp32, 8 nodes/block.
__global__ __launch_bounds__(256) void gemm2_kernel(
        const float* __restrict__ hact, const float* __restrict__ W2,
        const float* __restrict__ a_src2, const float* __restrict__ a_dst2,
        float* __restrict__ h2, float* __restrict__ as2, float* __restrict__ ad2, int N) {
    __shared__ float xs[8][256];
    int t = threadIdx.x;
    int node0 = blockIdx.x * 8;
    for (int i = t; i < 8 * 256; i += 256) {
        int r = i >> 8, c = i & 255;
        int gn = node0 + r;
        xs[r][c] = (gn < N) ? hact[(size_t)gn * 256 + c] : 0.f;
    }
    __syncthreads();
    int r = t >> 5, c = t & 31;
    float acc = 0.f;
    for (int k = 0; k < 256; k += 4) {
        float4 xv = *reinterpret_cast<const float4*>(&xs[r][k]);
        acc = fmaf(xv.x, W2[(k + 0) * 32 + c], acc);
        acc = fmaf(xv.y, W2[(k + 1) * 32 + c], acc);
        acc = fmaf(xv.z, W2[(k + 2) * 32 + c], acc);
        acc = fmaf(xv.w, W2[(k + 3) * 32 + c], acc);
    }
    int gn = node0 + r;
    if (gn < N) {
        h2[(size_t)gn * 32 + c] = acc;
        float vs = acc * a_src2[c];
        float vd = acc * a_dst2[c];
#pragma unroll
        for (int s = 16; s > 0; s >>= 1) {
            vs += __shfl_down(vs, s, 32);
            vd += __shfl_down(vd, s, 32);
        }
        if (c == 0) { as2[gn] = vs; ad2[gn] = vd; }
    }
}

// Layer-2 aggregation + bias + log_softmax. 32-lane group per node.
__global__ __launch_bounds__(256) void agg2_kernel(
        const float* __restrict__ h2,
        const float* __restrict__ as2, const float* __restrict__ ad2,
        const float* __restrict__ b2,
        const int* __restrict__ off, const int* __restrict__ esrc,
        float* __restrict__ out, int N) {
    int t = threadIdx.x;
    int g = t >> 5, c = t & 31;
    int node = blockIdx.x * 8 + g;
    if (node >= N) return;
    int beg = off[node], end = off[node + 1];
    float adv = ad2[node];
    float m = -3.0e38f, dnm = 0.f, acc = 0.f;
    for (int j = beg; j < end; j++) {
        int s = esrc[j];
        float e = as2[s] + adv;
        e = (e > 0.f) ? e : 0.2f * e;
        float nm = fmaxf(m, e);
        float scl = __expf(m - nm);
        float w = __expf(e - nm);
        dnm = dnm * scl + w;
        acc = acc * scl + w * h2[(size_t)s * 32 + c];
        m = nm;
    }
    float v = acc / (dnm + 1e-16f) + b2[c];
    float mx = v;
#pragma unroll
    for (int s = 16; s > 0; s >>= 1) mx = fmaxf(mx, __shfl_xor(mx, s, 32));
    float sum = __expf(v - mx);
#pragma unroll
    for (int s = 16; s > 0; s >>= 1) sum += __shfl_xor(sum, s, 32);
    out[(size_t)node * 32 + c] = (v - mx) - __logf(sum);
}

extern "C" void kernel_launch(void* const* d_in, const int* in_sizes, int n_in,
                              void* d_out, int out_size, void* d_ws, size_t ws_size,
                              hipStream_t stream) {
    const float* x      = (const float*)d_in[0];
    const void*  ei     = d_in[1];
    const float* W1     = (const float*)d_in[2];
    const float* a_src1 = (const float*)d_in[3];
    const float* a_dst1 = (const float*)d_in[4];
    const float* b1     = (const float*)d_in[5];
    const float* W2     = (const float*)d_in[6];
    const float* a_src2 = (const float*)d_in[7];
    const float* a_dst2 = (const float*)d_in[8];
    const float* b2     = (const float*)d_in[9];
    const int N  = in_sizes[0] / 256;   // 50000
    const int E  = in_sizes[1] / 2;     // 500000
    const int ET = E + N;
    float* outp = (float*)d_out;
    (void)n_in; (void)out_size; (void)ws_size;

    char* ws = (char*)d_ws;
    size_t o = 0;
    auto alloc = [&](size_t bytes) -> void* {
        void* p = ws + o;
        o += (bytes + 255) & ~(size_t)255;
        return p;
    };
    int*    flag   = (int*)alloc(4);
    int*    src32  = (int*)alloc((size_t)ET * 4);
    int*    dst32  = (int*)alloc((size_t)ET * 4);
    int*    deg    = (int*)alloc((size_t)2 * N * 4);
    int*    cursor = deg + N;
    int*    off    = (int*)alloc((size_t)(N + 1) * 4);
    int*    esrc   = (int*)alloc((size_t)ET * 4);
    ushort* xb     = (ushort*)alloc((size_t)N * 256 * 2);
    ushort* w1t    = (ushort*)alloc((size_t)256 * 256 * 2);
    ushort* h1b    = (ushort*)alloc((size_t)N * 256 * 2);
    float*  as1    = (float*)alloc((size_t)N * 8 * 4);
    float*  ad1    = (float*)alloc((size_t)N * 8 * 4);
    float*  hact   = (float*)alloc((size_t)N * 256 * 4);
    float*  h2     = (float*)alloc((size_t)N * 32 * 4);
    float*  as2    = (float*)alloc((size_t)N * 4);
    float*  ad2    = (float*)alloc((size_t)N * 4);

    zero_kernel<<<(2 * N + 255) / 256, 256, 0, stream>>>(deg, 2 * N);
    detect_kernel<<<1, 256, 0, stream>>>((const int*)ei, flag);
    decode_degree_kernel<<<(ET + 255) / 256, 256, 0, stream>>>(ei, E, ET, N, flag,
                                                               src32, dst32, deg);
    scan_kernel<<<1, 1024, 0, stream>>>(deg, off, N);
    scatter_kernel<<<(ET + 255) / 256, 256, 0, stream>>>(src32, dst32, ET, off,
                                                         cursor, esrc);

    long nx = (long)N * 256;
    convert_x<<<(int)((nx / 8 + 255) / 256), 256, 0, stream>>>(x, xb, nx);
    convert_w1t<<<dim3(8, 8), 256, 0, stream>>>(W1, w1t);
    gemm1_mfma<<<dim3((N + 127) / 128, 2), 256, 0, stream>>>(xb, w1t, h1b, N);
    alpha1_kernel<<<(N + 7) / 8, 256, 0, stream>>>(h1b, a_src1, a_dst1, as1, ad1, N);
    agg1_kernel<<<N, 256, 0, stream>>>(h1b, as1, ad1, b1, off, esrc, hact, N);
    gemm2_kernel<<<(N + 7) / 8, 256, 0, stream>>>(hact, W2, a_src2, a_dst2,
                                                  h2, as2, ad2, N);
    agg2_kernel<<<(N + 7) / 8, 256, 0, stream>>>(h2, as2, ad2, b2, off, esrc,
                                                 outp, N);
}

// Round 5
// 348.989 us; speedup vs baseline: 1.5146x; 1.0861x over previous
//
#include <hip/hip_runtime.h>
#include <math.h>

// ---------------------------------------------------------------------------
// GAT 2-layer forward (N=50000, F_in=256, H1=8, C1=32, C2=32, E=500000).
// R4: aggregation kernels restructured — lane j owns edge j (one exp per
// (edge,head), 32x fewer), shuffle reductions replace serial LDS scans,
// FMA loop unrolled x4 with 4 partial accumulators + float4 weight broadcast
// from LDS (conflict-free). GEMM1 stays bf16 MFMA.
// ---------------------------------------------------------------------------

typedef __attribute__((ext_vector_type(8))) short bf16x8;
typedef __attribute__((ext_vector_type(4))) float f32x4;

__device__ __forceinline__ float bf2f(ushort u) {
    union { uint i; float f; } v; v.i = ((uint)u) << 16; return v.f;
}
__device__ __forceinline__ ushort f2bf(float f) {  // round-to-nearest-even
    union { float f; uint i; } v; v.f = f;
    uint r = v.i + 0x7FFFu + ((v.i >> 16) & 1u);
    return (ushort)(r >> 16);
}

__global__ void zero_kernel(int* p, int n) {
    int i = blockIdx.x * blockDim.x + threadIdx.x;
    if (i < n) p[i] = 0;
}

// int64 little-endian values < 2^31 => every odd 32-bit word is 0.
__global__ void detect_kernel(const int* ei32, int* flag) {
    __shared__ int cnt;
    if (threadIdx.x == 0) cnt = 0;
    __syncthreads();
    int nz = 0;
    for (int i = threadIdx.x; i < 1024; i += blockDim.x)
        if (ei32[2 * i + 1] != 0) nz++;
    atomicAdd(&cnt, nz);
    __syncthreads();
    if (threadIdx.x == 0) *flag = (cnt > 16) ? 1 : 0;  // 1 => int32 layout
}

__global__ void decode_degree_kernel(const void* ei, int E, int ET, int N,
                                     const int* __restrict__ flag,
                                     int* __restrict__ src, int* __restrict__ dst,
                                     int* __restrict__ deg) {
    int k = blockIdx.x * blockDim.x + threadIdx.x;
    if (k >= ET) return;
    int s, d;
    if (k < E) {
        if (*flag) {
            const int* p = (const int*)ei;
            s = p[k]; d = p[E + k];
        } else {
            const long long* p = (const long long*)ei;
            s = (int)p[k]; d = (int)p[E + k];
        }
    } else {
        s = d = k - E;  // self-loops appended
    }
    s = min(max(s, 0), N - 1);
    d = min(max(d, 0), N - 1);
    src[k] = s; dst[k] = d;
    atomicAdd(&deg[d], 1);
}

// Exclusive prefix sum: serial per-thread chunks + one 1024-wide scan.
__global__ __launch_bounds__(1024) void scan_kernel(const int* __restrict__ deg,
                                                    int* __restrict__ off, int n) {
    __shared__ int partial[1024];
    int t = threadIdx.x;
    int per = (n + 1023) / 1024;
    int b0 = t * per;
    int e0 = min(b0 + per, n);
    int s = 0;
    for (int i = b0; i < e0; i++) s += deg[i];
    partial[t] = s;
    __syncthreads();
    for (int st = 1; st < 1024; st <<= 1) {
        int v = (t >= st) ? partial[t - st] : 0;
        __syncthreads();
        partial[t] += v;
        __syncthreads();
    }
    int run = partial[t] - s;
    if (t == 0) off[0] = 0;
    for (int i = b0; i < e0; i++) { run += deg[i]; off[i + 1] = run; }
}

__global__ void scatter_kernel(const int* __restrict__ src, const int* __restrict__ dst,
                               int ET, const int* __restrict__ off,
                               int* __restrict__ cursor, int* __restrict__ esrc) {
    int k = blockIdx.x * blockDim.x + threadIdx.x;
    if (k >= ET) return;
    int d = dst[k];
    int p = atomicAdd(&cursor[d], 1);
    esrc[off[d] + p] = src[k];
}

// x fp32 -> bf16, 8 elems/thread.
__global__ void convert_x(const float* __restrict__ x, ushort* __restrict__ xb, long n) {
    long i = ((long)blockIdx.x * blockDim.x + threadIdx.x) * 8;
    if (i >= n) return;
    float4 a = *(const float4*)&x[i];
    float4 b = *(const float4*)&x[i + 4];
    uint4 o;
    o.x = (uint)f2bf(a.x) | ((uint)f2bf(a.y) << 16);
    o.y = (uint)f2bf(a.z) | ((uint)f2bf(a.w) << 16);
    o.z = (uint)f2bf(b.x) | ((uint)f2bf(b.y) << 16);
    o.w = (uint)f2bf(b.z) | ((uint)f2bf(b.w) << 16);
    *(uint4*)&xb[i] = o;
}

// W1[256][256] fp32 -> w1t[256][256] bf16 transposed (w1t[n][k] = W1[k][n]).
__global__ __launch_bounds__(256) void convert_w1t(const float* __restrict__ W1,
                                                   ushort* __restrict__ w1t) {
    __shared__ float tile[32][33];
    int tx = threadIdx.x & 31, ty = threadIdx.x >> 5;
    int bx = blockIdx.x, by = blockIdx.y;
    for (int i = 0; i < 32; i += 8)
        tile[ty + i][tx] = W1[(by * 32 + ty + i) * 256 + bx * 32 + tx];
    __syncthreads();
    for (int i = 0; i < 32; i += 8)
        w1t[(bx * 32 + ty + i) * 256 + by * 32 + tx] = f2bf(tile[tx][ty + i]);
}

// h1 = x @ W1 via bf16 MFMA. 128x128 tile, BK=64, 4 waves (2x2), 4x4 frags.
#define LDA 72
__global__ __launch_bounds__(256) void gemm1_mfma(
        const ushort* __restrict__ xb,    // [N][256] bf16
        const ushort* __restrict__ w1t,   // [256][256] bf16 (n-major)
        ushort* __restrict__ h1b,         // [N][256] bf16 out
        int N) {
    __shared__ ushort Al[128 * LDA];
    __shared__ ushort Bl[128 * LDA];
    int t = threadIdx.x;
    int row0 = blockIdx.x * 128;
    int n0 = blockIdx.y * 128;
    int lane = t & 63, wid = t >> 6;
    int wr = wid >> 1, wc = wid & 1;

    f32x4 acc[4][4] = {};

    int sr = t >> 1, scs = (t & 1) * 32;
    for (int k0 = 0; k0 < 256; k0 += 64) {
        {
            int gr = row0 + sr;
            uint4 v0 = {0,0,0,0}, v1 = {0,0,0,0}, v2 = {0,0,0,0}, v3 = {0,0,0,0};
            if (gr < N) {
                const uint4* g = (const uint4*)(xb + (size_t)gr * 256 + k0 + scs);
                v0 = g[0]; v1 = g[1]; v2 = g[2]; v3 = g[3];
            }
            uint4* d = (uint4*)&Al[sr * LDA + scs];
            d[0] = v0; d[1] = v1; d[2] = v2; d[3] = v3;
        }
        {
            const uint4* g = (const uint4*)(w1t + (size_t)(n0 + sr) * 256 + k0 + scs);
            uint4* d = (uint4*)&Bl[sr * LDA + scs];
            d[0] = g[0]; d[1] = g[1]; d[2] = g[2]; d[3] = g[3];
        }
        __syncthreads();

#pragma unroll
        for (int ks = 0; ks < 2; ks++) {
            int kk = ks * 32 + (lane >> 4) * 8;
            bf16x8 af[4], bfr[4];
#pragma unroll
            for (int mi = 0; mi < 4; mi++) {
                int r = wr * 64 + mi * 16 + (lane & 15);
                af[mi] = *(const bf16x8*)&Al[r * LDA + kk];
            }
#pragma unroll
            for (int ni = 0; ni < 4; ni++) {
                int r = wc * 64 + ni * 16 + (lane & 15);
                bfr[ni] = *(const bf16x8*)&Bl[r * LDA + kk];
            }
#pragma unroll
            for (int mi = 0; mi < 4; mi++)
#pragma unroll
                for (int ni = 0; ni < 4; ni++)
                    acc[mi][ni] = __builtin_amdgcn_mfma_f32_16x16x32_bf16(
                        af[mi], bfr[ni], acc[mi][ni], 0, 0, 0);
        }
        __syncthreads();
    }

    // C/D layout (m89/m91): col = lane&15, row = (lane>>4)*4 + j
#pragma unroll
    for (int mi = 0; mi < 4; mi++)
#pragma unroll
        for (int ni = 0; ni < 4; ni++) {
            int gc = n0 + wc * 64 + ni * 16 + (lane & 15);
#pragma unroll
            for (int j = 0; j < 4; j++) {
                int gr = row0 + wr * 64 + mi * 16 + (lane >> 4) * 4 + j;
                if (gr < N) h1b[(size_t)gr * 256 + gc] = f2bf(acc[mi][ni][j]);
            }
        }
}

// as1/ad1 per (node, head) from bf16 h1. 32-lane group per node.
__global__ __launch_bounds__(256) void alpha1_kernel(
        const ushort* __restrict__ h1b,
        const float* __restrict__ a_src1, const float* __restrict__ a_dst1,
        float* __restrict__ as1, float* __restrict__ ad1, int N) {
    int t = threadIdx.x;
    int g = t >> 5, l = t & 31;
    int node = blockIdx.x * 8 + g;
    if (node >= N) return;
    bf16x8 hv = *(const bf16x8*)&h1b[(size_t)node * 256 + l * 8];
    float s = 0.f, d = 0.f;
#pragma unroll
    for (int i = 0; i < 8; i++) {
        float h = bf2f((ushort)hv[i]);
        s = fmaf(h, a_src1[l * 8 + i], s);
        d = fmaf(h, a_dst1[l * 8 + i], d);
    }
    s += __shfl_xor(s, 1); s += __shfl_xor(s, 2);
    d += __shfl_xor(d, 1); d += __shfl_xor(d, 2);
    if ((l & 3) == 0) {
        as1[node * 8 + (l >> 2)] = s;
        ad1[node * 8 + (l >> 2)] = d;
    }
}

// Layer-1 aggregation, restructured: lane j of each 32-lane head-group owns
// edge j of the chunk (1 exp per (edge,head)); max/sum via shuffle reductions;
// weights broadcast from a group-private LDS row read as float4; FMA loop
// unrolled x4 with 4 partial accumulators (independent gathers in flight).
__global__ __launch_bounds__(256) void agg1_kernel(
        const ushort* __restrict__ h1b,
        const float* __restrict__ as1, const float* __restrict__ ad1,
        const float* __restrict__ b1,
        const int* __restrict__ off, const int* __restrict__ esrc,
        float* __restrict__ hact, int N) {
    int node = blockIdx.x;
    int t = threadIdx.x;
    int head = t >> 5, lane = t & 31;
    __shared__ float s_w[8][32];
    int beg = off[node], end = off[node + 1];
    float adv = ad1[node * 8 + head];
    const ushort* hcol = h1b + t;   // column base: h1b[s*256 + t]
    float m = -3.0e38f, dnm = 0.f;
    float a0 = 0.f, a1 = 0.f, a2 = 0.f, a3 = 0.f;
    for (int base = beg; base < end; base += 32) {
        int n_ch = min(32, end - base);
        float ej = -3.0e38f;
        if (lane < n_ch) {
            int sj = esrc[base + lane];
            float e = as1[sj * 8 + head] + adv;
            ej = (e > 0.f) ? e : 0.2f * e;   // leaky_relu(0.2)
        }
        float cm = ej;
#pragma unroll
        for (int s = 16; s > 0; s >>= 1) cm = fmaxf(cm, __shfl_xor(cm, s, 32));
        float nm = fmaxf(m, cm);
        float scl = __expf(m - nm);          // 0 on first chunk
        float wj = (lane < n_ch) ? __expf(ej - nm) : 0.f;
        float ws = wj;
#pragma unroll
        for (int s = 16; s > 0; s >>= 1) ws += __shfl_xor(ws, s, 32);
        dnm = dnm * scl + ws;
        a0 *= scl; a1 *= scl; a2 *= scl; a3 *= scl;
        s_w[head][lane] = wj;
        __syncthreads();   // all groups share the node => uniform trip count
        int j = 0;
        for (; j + 4 <= n_ch; j += 4) {
            float4 w4 = *(const float4*)&s_w[head][j];   // broadcast, no conflict
            int s0 = esrc[base + j + 0];
            int s1 = esrc[base + j + 1];
            int s2 = esrc[base + j + 2];
            int s3 = esrc[base + j + 3];
            float h0 = bf2f(hcol[s0 * 256]);
            float h1v = bf2f(hcol[s1 * 256]);
            float h2v = bf2f(hcol[s2 * 256]);
            float h3v = bf2f(hcol[s3 * 256]);
            a0 = fmaf(w4.x, h0, a0);
            a1 = fmaf(w4.y, h1v, a1);
            a2 = fmaf(w4.z, h2v, a2);
            a3 = fmaf(w4.w, h3v, a3);
        }
        for (; j < n_ch; j++) {
            float w = s_w[head][j];
            int s0 = esrc[base + j];
            a0 = fmaf(w, bf2f(hcol[s0 * 256]), a0);
        }
        __syncthreads();   // protect s_w before next chunk's write
        m = nm;
    }
    float outv = (a0 + a1) + (a2 + a3);
    outv = outv / (dnm + 1e-16f) + b1[t];
    hact[(size_t)node * 256 + t] = (outv > 0.f) ? outv : (__expf(outv) - 1.f);
}

// h2 = hact @ W2 ([N,256]@[256,32]) + alpha2. fp32, 8 nodes/block.
__global__ __launch_bounds__(256) void gemm2_kernel(
        const float* __restrict__ hact, const float* __restrict__ W2,
        const float* __restrict__ a_src2, const float* __restrict__ a_dst2,
        float* __restrict__ h2, float* __restrict__ as2, float* __restrict__ ad2, int N) {
    __shared__ float xs[8][256];
    int t = threadIdx.x;
    int node0 = blockIdx.x * 8;
    for (int i = t; i < 8 * 256; i += 256) {
        int r = i >> 8, c = i & 255;
        int gn = node0 + r;
        xs[r][c] = (gn < N) ? hact[(size_t)gn * 256 + c] : 0.f;
    }
    __syncthreads();
    int r = t >> 5, c = t & 31;
    float acc = 0.f;
    for (int k = 0; k < 256; k += 4) {
        float4 xv = *reinterpret_cast<const float4*>(&xs[r][k]);
        acc = fmaf(xv.x, W2[(k + 0) * 32 + c], acc);
        acc = fmaf(xv.y, W2[(k + 1) * 32 + c], acc);
        acc = fmaf(xv.z, W2[(k + 2) * 32 + c], acc);
        acc = fmaf(xv.w, W2[(k + 3) * 32 + c], acc);
    }
    int gn = node0 + r;
    if (gn < N) {
        h2[(size_t)gn * 32 + c] = acc;
        float vs = acc * a_src2[c];
        float vd = acc * a_dst2[c];
#pragma unroll
        for (int s = 16; s > 0; s >>= 1) {
            vs += __shfl_down(vs, s, 32);
            vd += __shfl_down(vd, s, 32);
        }
        if (c == 0) { as2[gn] = vs; ad2[gn] = vd; }
    }
}

// Layer-2 aggregation + bias + log_softmax. 32-lane group per node; lane j
// owns edge j's weight; shuffle broadcasts (groups have divergent trip
// counts so no block barrier is legal here).
__global__ __launch_bounds__(256) void agg2_kernel(
        const float* __restrict__ h2,
        const float* __restrict__ as2, const float* __restrict__ ad2,
        const float* __restrict__ b2,
        const int* __restrict__ off, const int* __restrict__ esrc,
        float* __restrict__ out, int N) {
    int t = threadIdx.x;
    int g = t >> 5, c = t & 31;
    int node = blockIdx.x * 8 + g;
    if (node >= N) return;
    int beg = off[node], end = off[node + 1];
    float adv = ad2[node];
    const float* hcol = h2 + c;
    float m = -3.0e38f, dnm = 0.f;
    float a0 = 0.f, a1 = 0.f, a2a = 0.f, a3 = 0.f;
    for (int base = beg; base < end; base += 32) {
        int n_ch = min(32, end - base);
        float ej = -3.0e38f;
        int sj = 0;
        if (c < n_ch) {
            sj = esrc[base + c];
            float e = as2[sj] + adv;
            ej = (e > 0.f) ? e : 0.2f * e;
        }
        float cm = ej;
#pragma unroll
        for (int s = 16; s > 0; s >>= 1) cm = fmaxf(cm, __shfl_xor(cm, s, 32));
        float nm = fmaxf(m, cm);
        float scl = __expf(m - nm);
        float wj = (c < n_ch) ? __expf(ej - nm) : 0.f;
        float ws = wj;
#pragma unroll
        for (int s = 16; s > 0; s >>= 1) ws += __shfl_xor(ws, s, 32);
        dnm = dnm * scl + ws;
        a0 *= scl; a1 *= scl; a2a *= scl; a3 *= scl;
        int j = 0;
        for (; j + 4 <= n_ch; j += 4) {
            float w0 = __shfl(wj, j + 0, 32);
            float w1 = __shfl(wj, j + 1, 32);
            float w2 = __shfl(wj, j + 2, 32);
            float w3 = __shfl(wj, j + 3, 32);
            int s0 = __shfl(sj, j + 0, 32);
            int s1 = __shfl(sj, j + 1, 32);
            int s2 = __shfl(sj, j + 2, 32);
            int s3 = __shfl(sj, j + 3, 32);
            float h0 = hcol[s0 * 32];
            float h1v = hcol[s1 * 32];
            float h2v = hcol[s2 * 32];
            float h3v = hcol[s3 * 32];
            a0 = fmaf(w0, h0, a0);
            a1 = fmaf(w1, h1v, a1);
            a2a = fmaf(w2, h2v, a2a);
            a3 = fmaf(w3, h3v, a3);
        }
        for (; j < n_ch; j++) {
            float w = __shfl(wj, j, 32);
            int s0 = __shfl(sj, j, 32);
            a0 = fmaf(w, hcol[s0 * 32], a0);
        }
        m = nm;
    }
    float v = ((a0 + a1) + (a2a + a3)) / (dnm + 1e-16f) + b2[c];
    float mx = v;
#pragma unroll
    for (int s = 16; s > 0; s >>= 1) mx = fmaxf(mx, __shfl_xor(mx, s, 32));
    float sum = __expf(v - mx);
#pragma unroll
    for (int s = 16; s > 0; s >>= 1) sum += __shfl_xor(sum, s, 32);
    out[(size_t)node * 32 + c] = (v - mx) - __logf(sum);
}

extern "C" void kernel_launch(void* const* d_in, const int* in_sizes, int n_in,
                              void* d_out, int out_size, void* d_ws, size_t ws_size,
                              hipStream_t stream) {
    const float* x      = (const float*)d_in[0];
    const void*  ei     = d_in[1];
    const float* W1     = (const float*)d_in[2];
    const float* a_src1 = (const float*)d_in[3];
    const float* a_dst1 = (const float*)d_in[4];
    const float* b1     = (const float*)d_in[5];
    const float* W2     = (const float*)d_in[6];
    const float* a_src2 = (const float*)d_in[7];
    const float* a_dst2 = (const float*)d_in[8];
    const float* b2     = (const float*)d_in[9];
    const int N  = in_sizes[0] / 256;   // 50000
    const int E  = in_sizes[1] / 2;     // 500000
    const int ET = E + N;
    float* outp = (float*)d_out;
    (void)n_in; (void)out_size; (void)ws_size;

    char* ws = (char*)d_ws;
    size_t o = 0;
    auto alloc = [&](size_t bytes) -> void* {
        void* p = ws + o;
        o += (bytes + 255) & ~(size_t)255;
        return p;
    };
    int*    flag   = (int*)alloc(4);
    int*    src32  = (int*)alloc((size_t)ET * 4);
    int*    dst32  = (int*)alloc((size_t)ET * 4);
    int*    deg    = (int*)alloc((size_t)2 * N * 4);
    int*    cursor = deg + N;
    int*    off    = (int*)alloc((size_t)(N + 1) * 4);
    int*    esrc   = (int*)alloc((size_t)ET * 4);
    ushort* xb     = (ushort*)alloc((size_t)N * 256 * 2);
    ushort* w1t    = (ushort*)alloc((size_t)256 * 256 * 2);
    ushort* h1b    = (ushort*)alloc((size_t)N * 256 * 2);
    float*  as1    = (float*)alloc((size_t)N * 8 * 4);
    float*  ad1    = (float*)alloc((size_t)N * 8 * 4);
    float*  hact   = (float*)alloc((size_t)N * 256 * 4);
    float*  h2     = (float*)alloc((size_t)N * 32 * 4);
    float*  as2    = (float*)alloc((size_t)N * 4);
    float*  ad2    = (float*)alloc((size_t)N * 4);

    zero_kernel<<<(2 * N + 255) / 256, 256, 0, stream>>>(deg, 2 * N);
    detect_kernel<<<1, 256, 0, stream>>>((const int*)ei, flag);
    decode_degree_kernel<<<(ET + 255) / 256, 256, 0, stream>>>(ei, E, ET, N, flag,
                                                               src32, dst32, deg);
    scan_kernel<<<1, 1024, 0, stream>>>(deg, off, N);
    scatter_kernel<<<(ET + 255) / 256, 256, 0, stream>>>(src32, dst32, ET, off,
                                                         cursor, esrc);

    long nx = (long)N * 256;
    convert_x<<<(int)((nx / 8 + 255) / 256), 256, 0, stream>>>(x, xb, nx);
    convert_w1t<<<dim3(8, 8), 256, 0, stream>>>(W1, w1t);
    gemm1_mfma<<<dim3((N + 127) / 128, 2), 256, 0, stream>>>(xb, w1t, h1b, N);
    alpha1_kernel<<<(N + 7) / 8, 256, 0, stream>>>(h1b, a_src1, a_dst1, as1, ad1, N);
    agg1_kernel<<<N, 256, 0, stream>>>(h1b, as1, ad1, b1, off, esrc, hact, N);
    gemm2_kernel<<<(N + 7) / 8, 256, 0, stream>>>(hact, W2, a_src2, a_dst2,
                                                  h2, as2, ad2, N);
    agg2_kernel<<<(N + 7) / 8, 256, 0, stream>>>(h2, as2, ad2, b2, off, esrc,
                                                 outp, N);
}

// Round 6
// 320.744 us; speedup vs baseline: 1.6480x; 1.0881x over previous
//
#include <hip/hip_runtime.h>
#include <math.h>

// ---------------------------------------------------------------------------
// GAT 2-layer forward (N=50000, F_in=256, H1=8, C1=32, C2=32, E=500000).
// R5: phase-split aggregation — per-edge normalized weights precomputed by
// shuffle-only softmax kernels (weights1/weights2), then pure gather-accum
// kernels (agg1b: uint2 bf16 gathers, 1 wave/node, no barriers; agg2b:
// unrolled f32 gathers + fused log_softmax). hact stored bf16; GEMM2 moved
// to bf16 MFMA. GEMM1 MFMA and CSR build unchanged from R4.
// ---------------------------------------------------------------------------

typedef __attribute__((ext_vector_type(8))) short bf16x8;
typedef __attribute__((ext_vector_type(4))) float f32x4;

__device__ __forceinline__ float bf2f(ushort u) {
    union { uint i; float f; } v; v.i = ((uint)u) << 16; return v.f;
}
__device__ __forceinline__ ushort f2bf(float f) {  // round-to-nearest-even
    union { float f; uint i; } v; v.f = f;
    uint r = v.i + 0x7FFFu + ((v.i >> 16) & 1u);
    return (ushort)(r >> 16);
}

__global__ void zero_kernel(int* p, int n) {
    int i = blockIdx.x * blockDim.x + threadIdx.x;
    if (i < n) p[i] = 0;
}

// int64 little-endian values < 2^31 => every odd 32-bit word is 0.
__global__ void detect_kernel(const int* ei32, int* flag) {
    __shared__ int cnt;
    if (threadIdx.x == 0) cnt = 0;
    __syncthreads();
    int nz = 0;
    for (int i = threadIdx.x; i < 1024; i += blockDim.x)
        if (ei32[2 * i + 1] != 0) nz++;
    atomicAdd(&cnt, nz);
    __syncthreads();
    if (threadIdx.x == 0) *flag = (cnt > 16) ? 1 : 0;  // 1 => int32 layout
}

__global__ void decode_degree_kernel(const void* ei, int E, int ET, int N,
                                     const int* __restrict__ flag,
                                     int* __restrict__ src, int* __restrict__ dst,
                                     int* __restrict__ deg) {
    int k = blockIdx.x * blockDim.x + threadIdx.x;
    if (k >= ET) return;
    int s, d;
    if (k < E) {
        if (*flag) {
            const int* p = (const int*)ei;
            s = p[k]; d = p[E + k];
        } else {
            const long long* p = (const long long*)ei;
            s = (int)p[k]; d = (int)p[E + k];
        }
    } else {
        s = d = k - E;  // self-loops appended
    }
    s = min(max(s, 0), N - 1);
    d = min(max(d, 0), N - 1);
    src[k] = s; dst[k] = d;
    atomicAdd(&deg[d], 1);
}

// Exclusive prefix sum: serial per-thread chunks + one 1024-wide scan.
__global__ __launch_bounds__(1024) void scan_kernel(const int* __restrict__ deg,
                                                    int* __restrict__ off, int n) {
    __shared__ int partial[1024];
    int t = threadIdx.x;
    int per = (n + 1023) / 1024;
    int b0 = t * per;
    int e0 = min(b0 + per, n);
    int s = 0;
    for (int i = b0; i < e0; i++) s += deg[i];
    partial[t] = s;
    __syncthreads();
    for (int st = 1; st < 1024; st <<= 1) {
        int v = (t >= st) ? partial[t - st] : 0;
        __syncthreads();
        partial[t] += v;
        __syncthreads();
    }
    int run = partial[t] - s;
    if (t == 0) off[0] = 0;
    for (int i = b0; i < e0; i++) { run += deg[i]; off[i + 1] = run; }
}

__global__ void scatter_kernel(const int* __restrict__ src, const int* __restrict__ dst,
                               int ET, const int* __restrict__ off,
                               int* __restrict__ cursor, int* __restrict__ esrc) {
    int k = blockIdx.x * blockDim.x + threadIdx.x;
    if (k >= ET) return;
    int d = dst[k];
    int p = atomicAdd(&cursor[d], 1);
    esrc[off[d] + p] = src[k];
}

// x fp32 -> bf16, 8 elems/thread.
__global__ void convert_x(const float* __restrict__ x, ushort* __restrict__ xb, long n) {
    long i = ((long)blockIdx.x * blockDim.x + threadIdx.x) * 8;
    if (i >= n) return;
    float4 a = *(const float4*)&x[i];
    float4 b = *(const float4*)&x[i + 4];
    uint4 o;
    o.x = (uint)f2bf(a.x) | ((uint)f2bf(a.y) << 16);
    o.y = (uint)f2bf(a.z) | ((uint)f2bf(a.w) << 16);
    o.z = (uint)f2bf(b.x) | ((uint)f2bf(b.y) << 16);
    o.w = (uint)f2bf(b.z) | ((uint)f2bf(b.w) << 16);
    *(uint4*)&xb[i] = o;
}

// W1[256][256] fp32 -> w1t[256][256] bf16 transposed (w1t[n][k] = W1[k][n]).
__global__ __launch_bounds__(256) void convert_w1t(const float* __restrict__ W1,
                                                   ushort* __restrict__ w1t) {
    __shared__ float tile[32][33];
    int tx = threadIdx.x & 31, ty = threadIdx.x >> 5;
    int bx = blockIdx.x, by = blockIdx.y;
    for (int i = 0; i < 32; i += 8)
        tile[ty + i][tx] = W1[(by * 32 + ty + i) * 256 + bx * 32 + tx];
    __syncthreads();
    for (int i = 0; i < 32; i += 8)
        w1t[(bx * 32 + ty + i) * 256 + by * 32 + tx] = f2bf(tile[tx][ty + i]);
}

// W2[256][32] fp32 -> w2t[32][256] bf16 transposed (w2t[c][k] = W2[k][c]).
__global__ __launch_bounds__(256) void convert_w2t(const float* __restrict__ W2,
                                                   ushort* __restrict__ w2t) {
    int idx = blockIdx.x * 256 + threadIdx.x;   // 32 blocks x 256 = 8192
    int c = idx >> 8, k = idx & 255;
    w2t[idx] = f2bf(W2[k * 32 + c]);
}

// h1 = x @ W1 via bf16 MFMA. 128x128 tile, BK=64, 4 waves (2x2), 4x4 frags.
#define LDA 72
__global__ __launch_bounds__(256) void gemm1_mfma(
        const ushort* __restrict__ xb,    // [N][256] bf16
        const ushort* __restrict__ w1t,   // [256][256] bf16 (n-major)
        ushort* __restrict__ h1b,         // [N][256] bf16 out
        int N) {
    __shared__ ushort Al[128 * LDA];
    __shared__ ushort Bl[128 * LDA];
    int t = threadIdx.x;
    int row0 = blockIdx.x * 128;
    int n0 = blockIdx.y * 128;
    int lane = t & 63, wid = t >> 6;
    int wr = wid >> 1, wc = wid & 1;

    f32x4 acc[4][4] = {};

    int sr = t >> 1, scs = (t & 1) * 32;
    for (int k0 = 0; k0 < 256; k0 += 64) {
        {
            int gr = row0 + sr;
            uint4 v0 = {0,0,0,0}, v1 = {0,0,0,0}, v2 = {0,0,0,0}, v3 = {0,0,0,0};
            if (gr < N) {
                const uint4* g = (const uint4*)(xb + (size_t)gr * 256 + k0 + scs);
                v0 = g[0]; v1 = g[1]; v2 = g[2]; v3 = g[3];
            }
            uint4* d = (uint4*)&Al[sr * LDA + scs];
            d[0] = v0; d[1] = v1; d[2] = v2; d[3] = v3;
        }
        {
            const uint4* g = (const uint4*)(w1t + (size_t)(n0 + sr) * 256 + k0 + scs);
            uint4* d = (uint4*)&Bl[sr * LDA + scs];
            d[0] = g[0]; d[1] = g[1]; d[2] = g[2]; d[3] = g[3];
        }
        __syncthreads();

#pragma unroll
        for (int ks = 0; ks < 2; ks++) {
            int kk = ks * 32 + (lane >> 4) * 8;
            bf16x8 af[4], bfr[4];
#pragma unroll
            for (int mi = 0; mi < 4; mi++) {
                int r = wr * 64 + mi * 16 + (lane & 15);
                af[mi] = *(const bf16x8*)&Al[r * LDA + kk];
            }
#pragma unroll
            for (int ni = 0; ni < 4; ni++) {
                int r = wc * 64 + ni * 16 + (lane & 15);
                bfr[ni] = *(const bf16x8*)&Bl[r * LDA + kk];
            }
#pragma unroll
            for (int mi = 0; mi < 4; mi++)
#pragma unroll
                for (int ni = 0; ni < 4; ni++)
                    acc[mi][ni] = __builtin_amdgcn_mfma_f32_16x16x32_bf16(
                        af[mi], bfr[ni], acc[mi][ni], 0, 0, 0);
        }
        __syncthreads();
    }

    // C/D layout (m89/m91): col = lane&15, row = (lane>>4)*4 + j
#pragma unroll
    for (int mi = 0; mi < 4; mi++)
#pragma unroll
        for (int ni = 0; ni < 4; ni++) {
            int gc = n0 + wc * 64 + ni * 16 + (lane & 15);
#pragma unroll
            for (int j = 0; j < 4; j++) {
                int gr = row0 + wr * 64 + mi * 16 + (lane >> 4) * 4 + j;
                if (gr < N) h1b[(size_t)gr * 256 + gc] = f2bf(acc[mi][ni][j]);
            }
        }
}

// as1/ad1 per (node, head) from bf16 h1. 32-lane group per node.
__global__ __launch_bounds__(256) void alpha1_kernel(
        const ushort* __restrict__ h1b,
        const float* __restrict__ a_src1, const float* __restrict__ a_dst1,
        float* __restrict__ as1, float* __restrict__ ad1, int N) {
    int t = threadIdx.x;
    int g = t >> 5, l = t & 31;
    int node = blockIdx.x * 8 + g;
    if (node >= N) return;
    bf16x8 hv = *(const bf16x8*)&h1b[(size_t)node * 256 + l * 8];
    float s = 0.f, d = 0.f;
#pragma unroll
    for (int i = 0; i < 8; i++) {
        float h = bf2f((ushort)hv[i]);
        s = fmaf(h, a_src1[l * 8 + i], s);
        d = fmaf(h, a_dst1[l * 8 + i], d);
    }
    s += __shfl_xor(s, 1); s += __shfl_xor(s, 2);
    d += __shfl_xor(d, 1); d += __shfl_xor(d, 2);
    if ((l & 3) == 0) {
        as1[node * 8 + (l >> 2)] = s;
        ad1[node * 8 + (l >> 2)] = d;
    }
}

// Layer-1 per-edge normalized attention weights. One block per dst node,
// 8 head-groups x 32 lanes; pass 1: exact max+sum via shuffles; pass 2:
// alf1[edge][head] = exp(e-m)/denom. No gathers of h1, no LDS, no barriers.
__global__ __launch_bounds__(256) void weights1_kernel(
        const float* __restrict__ as1, const float* __restrict__ ad1,
        const int* __restrict__ off, const int* __restrict__ esrc,
        float* __restrict__ alf1, int N) {
    int node = blockIdx.x;
    int t = threadIdx.x;
    int head = t >> 5, lane = t & 31;
    int beg = off[node], end = off[node + 1];
    float adv = ad1[node * 8 + head];
    float m = -3.0e38f, dnm = 0.f;
    for (int base = beg; base < end; base += 32) {
        int n_ch = min(32, end - base);
        float ej = -3.0e38f;
        if (lane < n_ch) {
            int sj = esrc[base + lane];
            float e = as1[sj * 8 + head] + adv;
            ej = (e > 0.f) ? e : 0.2f * e;
        }
        float cm = ej;
#pragma unroll
        for (int s = 16; s > 0; s >>= 1) cm = fmaxf(cm, __shfl_xor(cm, s, 32));
        float nm = fmaxf(m, cm);
        float scl = __expf(m - nm);
        float wj = (lane < n_ch) ? __expf(ej - nm) : 0.f;
        float ws = wj;
#pragma unroll
        for (int s = 16; s > 0; s >>= 1) ws += __shfl_xor(ws, s, 32);
        dnm = dnm * scl + ws;
        m = nm;
    }
    float inv = 1.f / (dnm + 1e-16f);
    for (int base = beg; base < end; base += 32) {
        int n_ch = min(32, end - base);
        if (lane < n_ch) {
            int sj = esrc[base + lane];
            float e = as1[sj * 8 + head] + adv;
            e = (e > 0.f) ? e : 0.2f * e;
            alf1[(size_t)(base + lane) * 8 + head] = __expf(e - m) * inv;
        }
    }
}

// Layer-1 gather-accumulate: one 64-lane wave per node, 4 channels/lane via
// uint2 bf16 loads (512B per wave per edge), edge loop unrolled x4 with
// independent chains. Weights already normalized. Fuses +b1, elu, bf16 store.
__global__ __launch_bounds__(256) void agg1b_kernel(
        const ushort* __restrict__ h1b, const float* __restrict__ alf1,
        const float* __restrict__ b1,
        const int* __restrict__ off, const int* __restrict__ esrc,
        ushort* __restrict__ hactb, int N) {
    int t = threadIdx.x;
    int node = blockIdx.x * 4 + (t >> 6);
    int lane = t & 63;
    if (node >= N) return;
    int beg = off[node], end = off[node + 1];
    int ch0 = lane * 4;
    int head = lane >> 3;              // ch0/32
    const ushort* hb = h1b + ch0;
    const float* af = alf1 + head;
    float c0 = 0.f, c1 = 0.f, c2 = 0.f, c3 = 0.f;
    int j = beg;
    for (; j + 4 <= end; j += 4) {
        int s0 = esrc[j + 0], s1 = esrc[j + 1], s2 = esrc[j + 2], s3 = esrc[j + 3];
        float w0 = af[(size_t)(j + 0) * 8];
        float w1 = af[(size_t)(j + 1) * 8];
        float w2 = af[(size_t)(j + 2) * 8];
        float w3 = af[(size_t)(j + 3) * 8];
        uint2 v0 = *(const uint2*)(hb + (size_t)s0 * 256);
        uint2 v1 = *(const uint2*)(hb + (size_t)s1 * 256);
        uint2 v2 = *(const uint2*)(hb + (size_t)s2 * 256);
        uint2 v3 = *(const uint2*)(hb + (size_t)s3 * 256);
        c0 = fmaf(w0, bf2f((ushort)(v0.x & 0xffffu)), c0);
        c1 = fmaf(w0, bf2f((ushort)(v0.x >> 16)), c1);
        c2 = fmaf(w0, bf2f((ushort)(v0.y & 0xffffu)), c2);
        c3 = fmaf(w0, bf2f((ushort)(v0.y >> 16)), c3);
        c0 = fmaf(w1, bf2f((ushort)(v1.x & 0xffffu)), c0);
        c1 = fmaf(w1, bf2f((ushort)(v1.x >> 16)), c1);
        c2 = fmaf(w1, bf2f((ushort)(v1.y & 0xffffu)), c2);
        c3 = fmaf(w1, bf2f((ushort)(v1.y >> 16)), c3);
        c0 = fmaf(w2, bf2f((ushort)(v2.x & 0xffffu)), c0);
        c1 = fmaf(w2, bf2f((ushort)(v2.x >> 16)), c1);
        c2 = fmaf(w2, bf2f((ushort)(v2.y & 0xffffu)), c2);
        c3 = fmaf(w2, bf2f((ushort)(v2.y >> 16)), c3);
        c0 = fmaf(w3, bf2f((ushort)(v3.x & 0xffffu)), c0);
        c1 = fmaf(w3, bf2f((ushort)(v3.x >> 16)), c1);
        c2 = fmaf(w3, bf2f((ushort)(v3.y & 0xffffu)), c2);
        c3 = fmaf(w3, bf2f((ushort)(v3.y >> 16)), c3);
    }
    for (; j < end; j++) {
        int s0 = esrc[j];
        float w = af[(size_t)j * 8];
        uint2 v = *(const uint2*)(hb + (size_t)s0 * 256);
        c0 = fmaf(w, bf2f((ushort)(v.x & 0xffffu)), c0);
        c1 = fmaf(w, bf2f((ushort)(v.x >> 16)), c1);
        c2 = fmaf(w, bf2f((ushort)(v.y & 0xffffu)), c2);
        c3 = fmaf(w, bf2f((ushort)(v.y >> 16)), c3);
    }
    float4 bv = *(const float4*)&b1[ch0];
    float o0 = c0 + bv.x, o1 = c1 + bv.y, o2 = c2 + bv.z, o3 = c3 + bv.w;
    o0 = (o0 > 0.f) ? o0 : (__expf(o0) - 1.f);
    o1 = (o1 > 0.f) ? o1 : (__expf(o1) - 1.f);
    o2 = (o2 > 0.f) ? o2 : (__expf(o2) - 1.f);
    o3 = (o3 > 0.f) ? o3 : (__expf(o3) - 1.f);
    uint2 r;
    r.x = (uint)f2bf(o0) | ((uint)f2bf(o1) << 16);
    r.y = (uint)f2bf(o2) | ((uint)f2bf(o3) << 16);
    *(uint2*)(hactb + (size_t)node * 256 + ch0) = r;
}

// h2 = hactb @ W2 via bf16 MFMA. Tile 128x32, BK=64, 4 waves each owning a
// 32x32 m-subtile (2x2 frags). Output f32.
__global__ __launch_bounds__(256) void gemm2_mfma(
        const ushort* __restrict__ hactb,  // [N][256] bf16
        const ushort* __restrict__ w2t,    // [32][256] bf16 (c-major)
        float* __restrict__ h2, int N) {
    __shared__ ushort Al[128 * LDA];
    __shared__ ushort Bl[32 * LDA];
    int t = threadIdx.x;
    int row0 = blockIdx.x * 128;
    int lane = t & 63, wid = t >> 6;

    f32x4 acc[2][2] = {};

    int sr = t >> 1, scs = (t & 1) * 32;
    for (int k0 = 0; k0 < 256; k0 += 64) {
        {
            int gr = row0 + sr;
            uint4 v0 = {0,0,0,0}, v1 = {0,0,0,0}, v2 = {0,0,0,0}, v3 = {0,0,0,0};
            if (gr < N) {
                const uint4* g = (const uint4*)(hactb + (size_t)gr * 256 + k0 + scs);
                v0 = g[0]; v1 = g[1]; v2 = g[2]; v3 = g[3];
            }
            uint4* d = (uint4*)&Al[sr * LDA + scs];
            d[0] = v0; d[1] = v1; d[2] = v2; d[3] = v3;
        }
        if (t < 64) {
            const uint4* g = (const uint4*)(w2t + (size_t)sr * 256 + k0 + scs);
            uint4* d = (uint4*)&Bl[sr * LDA + scs];
            d[0] = g[0]; d[1] = g[1]; d[2] = g[2]; d[3] = g[3];
        }
        __syncthreads();

#pragma unroll
        for (int ks = 0; ks < 2; ks++) {
            int kk = ks * 32 + (lane >> 4) * 8;
            bf16x8 af[2], bfr[2];
#pragma unroll
            for (int mi = 0; mi < 2; mi++) {
                int r = wid * 32 + mi * 16 + (lane & 15);
                af[mi] = *(const bf16x8*)&Al[r * LDA + kk];
            }
#pragma unroll
            for (int ni = 0; ni < 2; ni++) {
                int r = ni * 16 + (lane & 15);
                bfr[ni] = *(const bf16x8*)&Bl[r * LDA + kk];
            }
#pragma unroll
            for (int mi = 0; mi < 2; mi++)
#pragma unroll
                for (int ni = 0; ni < 2; ni++)
                    acc[mi][ni] = __builtin_amdgcn_mfma_f32_16x16x32_bf16(
                        af[mi], bfr[ni], acc[mi][ni], 0, 0, 0);
        }
        __syncthreads();
    }

#pragma unroll
    for (int mi = 0; mi < 2; mi++)
#pragma unroll
        for (int ni = 0; ni < 2; ni++) {
            int gc = ni * 16 + (lane & 15);
#pragma unroll
            for (int j = 0; j < 4; j++) {
                int gr = row0 + wid * 32 + mi * 16 + (lane >> 4) * 4 + j;
                if (gr < N) h2[(size_t)gr * 32 + gc] = acc[mi][ni][j];
            }
        }
}

// as2/ad2 from h2: 8-lane group per node, float4 loads.
__global__ __launch_bounds__(256) void alpha2_kernel(
        const float* __restrict__ h2,
        const float* __restrict__ a_src2, const float* __restrict__ a_dst2,
        float* __restrict__ as2, float* __restrict__ ad2, int N) {
    int t = threadIdx.x;
    int g = t >> 3, q = t & 7;
    int node = blockIdx.x * 32 + g;
    if (node >= N) return;
    float4 v = *(const float4*)&h2[(size_t)node * 32 + q * 4];
    float4 sa = *(const float4*)&a_src2[q * 4];
    float4 da = *(const float4*)&a_dst2[q * 4];
    float s = v.x * sa.x + v.y * sa.y + v.z * sa.z + v.w * sa.w;
    float d = v.x * da.x + v.y * da.y + v.z * da.z + v.w * da.w;
    s += __shfl_xor(s, 1, 8); s += __shfl_xor(s, 2, 8); s += __shfl_xor(s, 4, 8);
    d += __shfl_xor(d, 1, 8); d += __shfl_xor(d, 2, 8); d += __shfl_xor(d, 4, 8);
    if (q == 0) { as2[node] = s; ad2[node] = d; }
}

// Layer-2 per-edge normalized weights. 32-lane group per node (8/block).
__global__ __launch_bounds__(256) void weights2_kernel(
        const float* __restrict__ as2, const float* __restrict__ ad2,
        const int* __restrict__ off, const int* __restrict__ esrc,
        float* __restrict__ alf2, int N) {
    int t = threadIdx.x;
    int g = t >> 5, lane = t & 31;
    int node = blockIdx.x * 8 + g;
    if (node >= N) return;
    int beg = off[node], end = off[node + 1];
    float adv = ad2[node];
    float m = -3.0e38f, dnm = 0.f;
    for (int base = beg; base < end; base += 32) {
        int n_ch = min(32, end - base);
        float ej = -3.0e38f;
        if (lane < n_ch) {
            float e = as2[esrc[base + lane]] + adv;
            ej = (e > 0.f) ? e : 0.2f * e;
        }
        float cm = ej;
#pragma unroll
        for (int s = 16; s > 0; s >>= 1) cm = fmaxf(cm, __shfl_xor(cm, s, 32));
        float nm = fmaxf(m, cm);
        float scl = __expf(m - nm);
        float wj = (lane < n_ch) ? __expf(ej - nm) : 0.f;
        float ws = wj;
#pragma unroll
        for (int s = 16; s > 0; s >>= 1) ws += __shfl_xor(ws, s, 32);
        dnm = dnm * scl + ws;
        m = nm;
    }
    float inv = 1.f / (dnm + 1e-16f);
    for (int base = beg; base < end; base += 32) {
        int n_ch = min(32, end - base);
        if (lane < n_ch) {
            float e = as2[esrc[base + lane]] + adv;
            e = (e > 0.f) ? e : 0.2f * e;
            alf2[base + lane] = __expf(e - m) * inv;
        }
    }
}

// Layer-2 gather-accumulate + bias + log_softmax. 32-lane group per node,
// unrolled x4, weights pre-normalized (no exp, no rescale chain).
__global__ __launch_bounds__(256) void agg2b_kernel(
        const float* __restrict__ h2, const float* __restrict__ alf2,
        const float* __restrict__ b2,
        const int* __restrict__ off, const int* __restrict__ esrc,
        float* __restrict__ out, int N) {
    int t = threadIdx.x;
    int g = t >> 5, c = t & 31;
    int node = blockIdx.x * 8 + g;
    if (node >= N) return;
    int beg = off[node], end = off[node + 1];
    const float* hcol = h2 + c;
    float a0 = 0.f, a1 = 0.f, a2 = 0.f, a3 = 0.f;
    int j = beg;
    for (; j + 4 <= end; j += 4) {
        int s0 = esrc[j + 0], s1 = esrc[j + 1], s2 = esrc[j + 2], s3 = esrc[j + 3];
        float w0 = alf2[j + 0], w1 = alf2[j + 1], w2 = alf2[j + 2], w3 = alf2[j + 3];
        a0 = fmaf(w0, hcol[(size_t)s0 * 32], a0);
        a1 = fmaf(w1, hcol[(size_t)s1 * 32], a1);
        a2 = fmaf(w2, hcol[(size_t)s2 * 32], a2);
        a3 = fmaf(w3, hcol[(size_t)s3 * 32], a3);
    }
    for (; j < end; j++)
        a0 = fmaf(alf2[j], hcol[(size_t)esrc[j] * 32], a0);
    float v = (a0 + a1) + (a2 + a3) + b2[c];
    float mx = v;
#pragma unroll
    for (int s = 16; s > 0; s >>= 1) mx = fmaxf(mx, __shfl_xor(mx, s, 32));
    float sum = __expf(v - mx);
#pragma unroll
    for (int s = 16; s > 0; s >>= 1) sum += __shfl_xor(sum, s, 32);
    out[(size_t)node * 32 + c] = (v - mx) - __logf(sum);
}

extern "C" void kernel_launch(void* const* d_in, const int* in_sizes, int n_in,
                              void* d_out, int out_size, void* d_ws, size_t ws_size,
                              hipStream_t stream) {
    const float* x      = (const float*)d_in[0];
    const void*  ei     = d_in[1];
    const float* W1     = (const float*)d_in[2];
    const float* a_src1 = (const float*)d_in[3];
    const float* a_dst1 = (const float*)d_in[4];
    const float* b1     = (const float*)d_in[5];
    const float* W2     = (const float*)d_in[6];
    const float* a_src2 = (const float*)d_in[7];
    const float* a_dst2 = (const float*)d_in[8];
    const float* b2     = (const float*)d_in[9];
    const int N  = in_sizes[0] / 256;   // 50000
    const int E  = in_sizes[1] / 2;     // 500000
    const int ET = E + N;
    float* outp = (float*)d_out;
    (void)n_in; (void)out_size; (void)ws_size;

    char* ws = (char*)d_ws;
    size_t o = 0;
    auto alloc = [&](size_t bytes) -> void* {
        void* p = ws + o;
        o += (bytes + 255) & ~(size_t)255;
        return p;
    };
    int*    flag   = (int*)alloc(4);
    int*    src32  = (int*)alloc((size_t)ET * 4);
    int*    dst32  = (int*)alloc((size_t)ET * 4);
    int*    deg    = (int*)alloc((size_t)2 * N * 4);
    int*    cursor = deg + N;
    int*    off    = (int*)alloc((size_t)(N + 1) * 4);
    int*    esrc   = (int*)alloc((size_t)ET * 4);
    ushort* xb     = (ushort*)alloc((size_t)N * 256 * 2);
    ushort* w1t    = (ushort*)alloc((size_t)256 * 256 * 2);
    ushort* w2t    = (ushort*)alloc((size_t)32 * 256 * 2);
    ushort* h1b    = (ushort*)alloc((size_t)N * 256 * 2);
    float*  as1    = (float*)alloc((size_t)N * 8 * 4);
    float*  ad1    = (float*)alloc((size_t)N * 8 * 4);
    float*  alf1   = (float*)alloc((size_t)ET * 8 * 4);
    ushort* hactb  = (ushort*)alloc((size_t)N * 256 * 2);
    float*  h2     = (float*)alloc((size_t)N * 32 * 4);
    float*  as2    = (float*)alloc((size_t)N * 4);
    float*  ad2    = (float*)alloc((size_t)N * 4);
    float*  alf2   = (float*)alloc((size_t)ET * 4);

    zero_kernel<<<(2 * N + 255) / 256, 256, 0, stream>>>(deg, 2 * N);
    detect_kernel<<<1, 256, 0, stream>>>((const int*)ei, flag);
    decode_degree_kernel<<<(ET + 255) / 256, 256, 0, stream>>>(ei, E, ET, N, flag,
                                                               src32, dst32, deg);
    scan_kernel<<<1, 1024, 0, stream>>>(deg, off, N);
    scatter_kernel<<<(ET + 255) / 256, 256, 0, stream>>>(src32, dst32, ET, off,
                                                         cursor, esrc);

    long nx = (long)N * 256;
    convert_x<<<(int)((nx / 8 + 255) / 256), 256, 0, stream>>>(x, xb, nx);
    convert_w1t<<<dim3(8, 8), 256, 0, stream>>>(W1, w1t);
    convert_w2t<<<32, 256, 0, stream>>>(W2, w2t);

    gemm1_mfma<<<dim3((N + 127) / 128, 2), 256, 0, stream>>>(xb, w1t, h1b, N);
    alpha1_kernel<<<(N + 7) / 8, 256, 0, stream>>>(h1b, a_src1, a_dst1, as1, ad1, N);
    weights1_kernel<<<N, 256, 0, stream>>>(as1, ad1, off, esrc, alf1, N);
    agg1b_kernel<<<(N + 3) / 4, 256, 0, stream>>>(h1b, alf1, b1, off, esrc, hactb, N);
    gemm2_mfma<<<(N + 127) / 128, 256, 0, stream>>>(hactb, w2t, h2, N);
    alpha2_kernel<<<(N + 31) / 32, 256, 0, stream>>>(h2, a_src2, a_dst2, as2, ad2, N);
    weights2_kernel<<<(N + 7) / 8, 256, 0, stream>>>(as2, ad2, off, esrc, alf2, N);
    agg2b_kernel<<<(N + 7) / 8, 256, 0, stream>>>(h2, alf2, b2, off, esrc, outp, N);
}

// Round 7
// 252.236 us; speedup vs baseline: 2.0956x; 1.2716x over previous
//
#include <hip/hip_runtime.h>
#include <math.h>

// ---------------------------------------------------------------------------
// GAT 2-layer forward (N=50000, F_in=256, H1=8, C1=32, C2=32, E=500000).
// R6: the single-block scan (80us, one CU busy, uncoalesced stride-49) is
// replaced by a 3-phase hierarchical scan (scanA block sums -> scanB scan of
// partials -> scanC per-block scan + offset), all coalesced, ~6us total.
// Everything else unchanged from R5.
// ---------------------------------------------------------------------------

typedef __attribute__((ext_vector_type(8))) short bf16x8;
typedef __attribute__((ext_vector_type(4))) float f32x4;

__device__ __forceinline__ float bf2f(ushort u) {
    union { uint i; float f; } v; v.i = ((uint)u) << 16; return v.f;
}
__device__ __forceinline__ ushort f2bf(float f) {  // round-to-nearest-even
    union { float f; uint i; } v; v.f = f;
    uint r = v.i + 0x7FFFu + ((v.i >> 16) & 1u);
    return (ushort)(r >> 16);
}

__global__ void zero_kernel(int* p, int n) {
    int i = blockIdx.x * blockDim.x + threadIdx.x;
    if (i < n) p[i] = 0;
}

// int64 little-endian values < 2^31 => every odd 32-bit word is 0.
__global__ void detect_kernel(const int* ei32, int* flag) {
    __shared__ int cnt;
    if (threadIdx.x == 0) cnt = 0;
    __syncthreads();
    int nz = 0;
    for (int i = threadIdx.x; i < 1024; i += blockDim.x)
        if (ei32[2 * i + 1] != 0) nz++;
    atomicAdd(&cnt, nz);
    __syncthreads();
    if (threadIdx.x == 0) *flag = (cnt > 16) ? 1 : 0;  // 1 => int32 layout
}

__global__ void decode_degree_kernel(const void* ei, int E, int ET, int N,
                                     const int* __restrict__ flag,
                                     int* __restrict__ src, int* __restrict__ dst,
                                     int* __restrict__ deg) {
    int k = blockIdx.x * blockDim.x + threadIdx.x;
    if (k >= ET) return;
    int s, d;
    if (k < E) {
        if (*flag) {
            const int* p = (const int*)ei;
            s = p[k]; d = p[E + k];
        } else {
            const long long* p = (const long long*)ei;
            s = (int)p[k]; d = (int)p[E + k];
        }
    } else {
        s = d = k - E;  // self-loops appended
    }
    s = min(max(s, 0), N - 1);
    d = min(max(d, 0), N - 1);
    src[k] = s; dst[k] = d;
    atomicAdd(&deg[d], 1);
}

// --- 3-phase hierarchical exclusive scan (coalesced, parallel) -------------
// Phase A: per-block (256-elem chunk) sums.
__global__ __launch_bounds__(256) void scanA_kernel(const int* __restrict__ deg,
                                                    int* __restrict__ bsum, int n) {
    int i = blockIdx.x * 256 + threadIdx.x;
    int v = (i < n) ? deg[i] : 0;
#pragma unroll
    for (int s = 1; s < 64; s <<= 1) v += __shfl_xor(v, s, 64);
    __shared__ int ws[4];
    int lane = threadIdx.x & 63, wid = threadIdx.x >> 6;
    if (lane == 0) ws[wid] = v;
    __syncthreads();
    if (threadIdx.x == 0) bsum[blockIdx.x] = ws[0] + ws[1] + ws[2] + ws[3];
}

// Phase B: exclusive scan of block sums (nb <= 1024), one block.
__global__ __launch_bounds__(1024) void scanB_kernel(int* __restrict__ bsum, int nb) {
    int t = threadIdx.x;
    int v = (t < nb) ? bsum[t] : 0;
    __shared__ int sm[1024];
    sm[t] = v;
    __syncthreads();
    for (int s = 1; s < 1024; s <<= 1) {
        int a = (t >= s) ? sm[t - s] : 0;
        __syncthreads();
        sm[t] += a;
        __syncthreads();
    }
    if (t < nb) bsum[t] = sm[t] - v;  // exclusive
}

// Phase C: per-block inclusive scan + block offset -> off[i+1]; off[0]=0.
__global__ __launch_bounds__(256) void scanC_kernel(const int* __restrict__ deg,
                                                    const int* __restrict__ bsum,
                                                    int* __restrict__ off, int n) {
    int t = threadIdx.x;
    int i = blockIdx.x * 256 + t;
    int v = (i < n) ? deg[i] : 0;
    int incl = v;
    int lane = t & 63, wid = t >> 6;
#pragma unroll
    for (int s = 1; s < 64; s <<= 1) {
        int a = __shfl_up(incl, s, 64);
        if (lane >= s) incl += a;
    }
    __shared__ int wsum[4];
    if (lane == 63) wsum[wid] = incl;
    __syncthreads();
    int wo = 0;
    for (int w = 0; w < wid; w++) wo += wsum[w];
    if (i < n) off[i + 1] = bsum[blockIdx.x] + wo + incl;
    if (i == 0) off[0] = 0;
}

__global__ void scatter_kernel(const int* __restrict__ src, const int* __restrict__ dst,
                               int ET, const int* __restrict__ off,
                               int* __restrict__ cursor, int* __restrict__ esrc) {
    int k = blockIdx.x * blockDim.x + threadIdx.x;
    if (k >= ET) return;
    int d = dst[k];
    int p = atomicAdd(&cursor[d], 1);
    esrc[off[d] + p] = src[k];
}

// x fp32 -> bf16, 8 elems/thread.
__global__ void convert_x(const float* __restrict__ x, ushort* __restrict__ xb, long n) {
    long i = ((long)blockIdx.x * blockDim.x + threadIdx.x) * 8;
    if (i >= n) return;
    float4 a = *(const float4*)&x[i];
    float4 b = *(const float4*)&x[i + 4];
    uint4 o;
    o.x = (uint)f2bf(a.x) | ((uint)f2bf(a.y) << 16);
    o.y = (uint)f2bf(a.z) | ((uint)f2bf(a.w) << 16);
    o.z = (uint)f2bf(b.x) | ((uint)f2bf(b.y) << 16);
    o.w = (uint)f2bf(b.z) | ((uint)f2bf(b.w) << 16);
    *(uint4*)&xb[i] = o;
}

// W1[256][256] fp32 -> w1t[256][256] bf16 transposed (w1t[n][k] = W1[k][n]).
__global__ __launch_bounds__(256) void convert_w1t(const float* __restrict__ W1,
                                                   ushort* __restrict__ w1t) {
    __shared__ float tile[32][33];
    int tx = threadIdx.x & 31, ty = threadIdx.x >> 5;
    int bx = blockIdx.x, by = blockIdx.y;
    for (int i = 0; i < 32; i += 8)
        tile[ty + i][tx] = W1[(by * 32 + ty + i) * 256 + bx * 32 + tx];
    __syncthreads();
    for (int i = 0; i < 32; i += 8)
        w1t[(bx * 32 + ty + i) * 256 + by * 32 + tx] = f2bf(tile[tx][ty + i]);
}

// W2[256][32] fp32 -> w2t[32][256] bf16 transposed (w2t[c][k] = W2[k][c]).
__global__ __launch_bounds__(256) void convert_w2t(const float* __restrict__ W2,
                                                   ushort* __restrict__ w2t) {
    int idx = blockIdx.x * 256 + threadIdx.x;   // 32 blocks x 256 = 8192
    int c = idx >> 8, k = idx & 255;
    w2t[idx] = f2bf(W2[k * 32 + c]);
}

// h1 = x @ W1 via bf16 MFMA. 128x128 tile, BK=64, 4 waves (2x2), 4x4 frags.
#define LDA 72
__global__ __launch_bounds__(256) void gemm1_mfma(
        const ushort* __restrict__ xb,    // [N][256] bf16
        const ushort* __restrict__ w1t,   // [256][256] bf16 (n-major)
        ushort* __restrict__ h1b,         // [N][256] bf16 out
        int N) {
    __shared__ ushort Al[128 * LDA];
    __shared__ ushort Bl[128 * LDA];
    int t = threadIdx.x;
    int row0 = blockIdx.x * 128;
    int n0 = blockIdx.y * 128;
    int lane = t & 63, wid = t >> 6;
    int wr = wid >> 1, wc = wid & 1;

    f32x4 acc[4][4] = {};

    int sr = t >> 1, scs = (t & 1) * 32;
    for (int k0 = 0; k0 < 256; k0 += 64) {
        {
            int gr = row0 + sr;
            uint4 v0 = {0,0,0,0}, v1 = {0,0,0,0}, v2 = {0,0,0,0}, v3 = {0,0,0,0};
            if (gr < N) {
                const uint4* g = (const uint4*)(xb + (size_t)gr * 256 + k0 + scs);
                v0 = g[0]; v1 = g[1]; v2 = g[2]; v3 = g[3];
            }
            uint4* d = (uint4*)&Al[sr * LDA + scs];
            d[0] = v0; d[1] = v1; d[2] = v2; d[3] = v3;
        }
        {
            const uint4* g = (const uint4*)(w1t + (size_t)(n0 + sr) * 256 + k0 + scs);
            uint4* d = (uint4*)&Bl[sr * LDA + scs];
            d[0] = g[0]; d[1] = g[1]; d[2] = g[2]; d[3] = g[3];
        }
        __syncthreads();

#pragma unroll
        for (int ks = 0; ks < 2; ks++) {
            int kk = ks * 32 + (lane >> 4) * 8;
            bf16x8 af[4], bfr[4];
#pragma unroll
            for (int mi = 0; mi < 4; mi++) {
                int r = wr * 64 + mi * 16 + (lane & 15);
                af[mi] = *(const bf16x8*)&Al[r * LDA + kk];
            }
#pragma unroll
            for (int ni = 0; ni < 4; ni++) {
                int r = wc * 64 + ni * 16 + (lane & 15);
                bfr[ni] = *(const bf16x8*)&Bl[r * LDA + kk];
            }
#pragma unroll
            for (int mi = 0; mi < 4; mi++)
#pragma unroll
                for (int ni = 0; ni < 4; ni++)
                    acc[mi][ni] = __builtin_amdgcn_mfma_f32_16x16x32_bf16(
                        af[mi], bfr[ni], acc[mi][ni], 0, 0, 0);
        }
        __syncthreads();
    }

    // C/D layout (m89/m91): col = lane&15, row = (lane>>4)*4 + j
#pragma unroll
    for (int mi = 0; mi < 4; mi++)
#pragma unroll
        for (int ni = 0; ni < 4; ni++) {
            int gc = n0 + wc * 64 + ni * 16 + (lane & 15);
#pragma unroll
            for (int j = 0; j < 4; j++) {
                int gr = row0 + wr * 64 + mi * 16 + (lane >> 4) * 4 + j;
                if (gr < N) h1b[(size_t)gr * 256 + gc] = f2bf(acc[mi][ni][j]);
            }
        }
}

// as1/ad1 per (node, head) from bf16 h1. 32-lane group per node.
__global__ __launch_bounds__(256) void alpha1_kernel(
        const ushort* __restrict__ h1b,
        const float* __restrict__ a_src1, const float* __restrict__ a_dst1,
        float* __restrict__ as1, float* __restrict__ ad1, int N) {
    int t = threadIdx.x;
    int g = t >> 5, l = t & 31;
    int node = blockIdx.x * 8 + g;
    if (node >= N) return;
    bf16x8 hv = *(const bf16x8*)&h1b[(size_t)node * 256 + l * 8];
    float s = 0.f, d = 0.f;
#pragma unroll
    for (int i = 0; i < 8; i++) {
        float h = bf2f((ushort)hv[i]);
        s = fmaf(h, a_src1[l * 8 + i], s);
        d = fmaf(h, a_dst1[l * 8 + i], d);
    }
    s += __shfl_xor(s, 1); s += __shfl_xor(s, 2);
    d += __shfl_xor(d, 1); d += __shfl_xor(d, 2);
    if ((l & 3) == 0) {
        as1[node * 8 + (l >> 2)] = s;
        ad1[node * 8 + (l >> 2)] = d;
    }
}

// Layer-1 per-edge normalized attention weights. One block per dst node,
// 8 head-groups x 32 lanes; pass 1: exact max+sum via shuffles; pass 2:
// alf1[edge][head] = exp(e-m)/denom. No gathers of h1, no LDS, no barriers.
__global__ __launch_bounds__(256) void weights1_kernel(
        const float* __restrict__ as1, const float* __restrict__ ad1,
        const int* __restrict__ off, const int* __restrict__ esrc,
        float* __restrict__ alf1, int N) {
    int node = blockIdx.x;
    int t = threadIdx.x;
    int head = t >> 5, lane = t & 31;
    int beg = off[node], end = off[node + 1];
    float adv = ad1[node * 8 + head];
    float m = -3.0e38f, dnm = 0.f;
    for (int base = beg; base < end; base += 32) {
        int n_ch = min(32, end - base);
        float ej = -3.0e38f;
        if (lane < n_ch) {
            int sj = esrc[base + lane];
            float e = as1[sj * 8 + head] + adv;
            ej = (e > 0.f) ? e : 0.2f * e;
        }
        float cm = ej;
#pragma unroll
        for (int s = 16; s > 0; s >>= 1) cm = fmaxf(cm, __shfl_xor(cm, s, 32));
        float nm = fmaxf(m, cm);
        float scl = __expf(m - nm);
        float wj = (lane < n_ch) ? __expf(ej - nm) : 0.f;
        float ws = wj;
#pragma unroll
        for (int s = 16; s > 0; s >>= 1) ws += __shfl_xor(ws, s, 32);
        dnm = dnm * scl + ws;
        m = nm;
    }
    float inv = 1.f / (dnm + 1e-16f);
    for (int base = beg; base < end; base += 32) {
        int n_ch = min(32, end - base);
        if (lane < n_ch) {
            int sj = esrc[base + lane];
            float e = as1[sj * 8 + head] + adv;
            e = (e > 0.f) ? e : 0.2f * e;
            alf1[(size_t)(base + lane) * 8 + head] = __expf(e - m) * inv;
        }
    }
}

// Layer-1 gather-accumulate: one 64-lane wave per node, 4 channels/lane via
// uint2 bf16 loads (512B per wave per edge), edge loop unrolled x4 with
// independent chains. Weights already normalized. Fuses +b1, elu, bf16 store.
__global__ __launch_bounds__(256) void agg1b_kernel(
        const ushort* __restrict__ h1b, const float* __restrict__ alf1,
        const float* __restrict__ b1,
        const int* __restrict__ off, const int* __restrict__ esrc,
        ushort* __restrict__ hactb, int N) {
    int t = threadIdx.x;
    int node = blockIdx.x * 4 + (t >> 6);
    int lane = t & 63;
    if (node >= N) return;
    int beg = off[node], end = off[node + 1];
    int ch0 = lane * 4;
    int head = lane >> 3;              // ch0/32
    const ushort* hb = h1b + ch0;
    const float* af = alf1 + head;
    float c0 = 0.f, c1 = 0.f, c2 = 0.f, c3 = 0.f;
    int j = beg;
    for (; j + 4 <= end; j += 4) {
        int s0 = esrc[j + 0], s1 = esrc[j + 1], s2 = esrc[j + 2], s3 = esrc[j + 3];
        float w0 = af[(size_t)(j + 0) * 8];
        float w1 = af[(size_t)(j + 1) * 8];
        float w2 = af[(size_t)(j + 2) * 8];
        float w3 = af[(size_t)(j + 3) * 8];
        uint2 v0 = *(const uint2*)(hb + (size_t)s0 * 256);
        uint2 v1 = *(const uint2*)(hb + (size_t)s1 * 256);
        uint2 v2 = *(const uint2*)(hb + (size_t)s2 * 256);
        uint2 v3 = *(const uint2*)(hb + (size_t)s3 * 256);
        c0 = fmaf(w0, bf2f((ushort)(v0.x & 0xffffu)), c0);
        c1 = fmaf(w0, bf2f((ushort)(v0.x >> 16)), c1);
        c2 = fmaf(w0, bf2f((ushort)(v0.y & 0xffffu)), c2);
        c3 = fmaf(w0, bf2f((ushort)(v0.y >> 16)), c3);
        c0 = fmaf(w1, bf2f((ushort)(v1.x & 0xffffu)), c0);
        c1 = fmaf(w1, bf2f((ushort)(v1.x >> 16)), c1);
        c2 = fmaf(w1, bf2f((ushort)(v1.y & 0xffffu)), c2);
        c3 = fmaf(w1, bf2f((ushort)(v1.y >> 16)), c3);
        c0 = fmaf(w2, bf2f((ushort)(v2.x & 0xffffu)), c0);
        c1 = fmaf(w2, bf2f((ushort)(v2.x >> 16)), c1);
        c2 = fmaf(w2, bf2f((ushort)(v2.y & 0xffffu)), c2);
        c3 = fmaf(w2, bf2f((ushort)(v2.y >> 16)), c3);
        c0 = fmaf(w3, bf2f((ushort)(v3.x & 0xffffu)), c0);
        c1 = fmaf(w3, bf2f((ushort)(v3.x >> 16)), c1);
        c2 = fmaf(w3, bf2f((ushort)(v3.y & 0xffffu)), c2);
        c3 = fmaf(w3, bf2f((ushort)(v3.y >> 16)), c3);
    }
    for (; j < end; j++) {
        int s0 = esrc[j];
        float w = af[(size_t)j * 8];
        uint2 v = *(const uint2*)(hb + (size_t)s0 * 256);
        c0 = fmaf(w, bf2f((ushort)(v.x & 0xffffu)), c0);
        c1 = fmaf(w, bf2f((ushort)(v.x >> 16)), c1);
        c2 = fmaf(w, bf2f((ushort)(v.y & 0xffffu)), c2);
        c3 = fmaf(w, bf2f((ushort)(v.y >> 16)), c3);
    }
    float4 bv = *(const float4*)&b1[ch0];
    float o0 = c0 + bv.x, o1 = c1 + bv.y, o2 = c2 + bv.z, o3 = c3 + bv.w;
    o0 = (o0 > 0.f) ? o0 : (__expf(o0) - 1.f);
    o1 = (o1 > 0.f) ? o1 : (__expf(o1) - 1.f);
    o2 = (o2 > 0.f) ? o2 : (__expf(o2) - 1.f);
    o3 = (o3 > 0.f) ? o3 : (__expf(o3) - 1.f);
    uint2 r;
    r.x = (uint)f2bf(o0) | ((uint)f2bf(o1) << 16);
    r.y = (uint)f2bf(o2) | ((uint)f2bf(o3) << 16);
    *(uint2*)(hactb + (size_t)node * 256 + ch0) = r;
}

// h2 = hactb @ W2 via bf16 MFMA. Tile 128x32, BK=64, 4 waves each owning a
// 32x32 m-subtile (2x2 frags). Output f32.
__global__ __launch_bounds__(256) void gemm2_mfma(
        const ushort* __restrict__ hactb,  // [N][256] bf16
        const ushort* __restrict__ w2t,    // [32][256] bf16 (c-major)
        float* __restrict__ h2, int N) {
    __shared__ ushort Al[128 * LDA];
    __shared__ ushort Bl[32 * LDA];
    int t = threadIdx.x;
    int row0 = blockIdx.x * 128;
    int lane = t & 63, wid = t >> 6;

    f32x4 acc[2][2] = {};

    int sr = t >> 1, scs = (t & 1) * 32;
    for (int k0 = 0; k0 < 256; k0 += 64) {
        {
            int gr = row0 + sr;
            uint4 v0 = {0,0,0,0}, v1 = {0,0,0,0}, v2 = {0,0,0,0}, v3 = {0,0,0,0};
            if (gr < N) {
                const uint4* g = (const uint4*)(hactb + (size_t)gr * 256 + k0 + scs);
                v0 = g[0]; v1 = g[1]; v2 = g[2]; v3 = g[3];
            }
            uint4* d = (uint4*)&Al[sr * LDA + scs];
            d[0] = v0; d[1] = v1; d[2] = v2; d[3] = v3;
        }
        if (t < 64) {
            const uint4* g = (const uint4*)(w2t + (size_t)sr * 256 + k0 + scs);
            uint4* d = (uint4*)&Bl[sr * LDA + scs];
            d[0] = g[0]; d[1] = g[1]; d[2] = g[2]; d[3] = g[3];
        }
        __syncthreads();

#pragma unroll
        for (int ks = 0; ks < 2; ks++) {
            int kk = ks * 32 + (lane >> 4) * 8;
            bf16x8 af[2], bfr[2];
#pragma unroll
            for (int mi = 0; mi < 2; mi++) {
                int r = wid * 32 + mi * 16 + (lane & 15);
                af[mi] = *(const bf16x8*)&Al[r * LDA + kk];
            }
#pragma unroll
            for (int ni = 0; ni < 2; ni++) {
                int r = ni * 16 + (lane & 15);
                bfr[ni] = *(const bf16x8*)&Bl[r * LDA + kk];
            }
#pragma unroll
            for (int mi = 0; mi < 2; mi++)
#pragma unroll
                for (int ni = 0; ni < 2; ni++)
                    acc[mi][ni] = __builtin_amdgcn_mfma_f32_16x16x32_bf16(
                        af[mi], bfr[ni], acc[mi][ni], 0, 0, 0);
        }
        __syncthreads();
    }

#pragma unroll
    for (int mi = 0; mi < 2; mi++)
#pragma unroll
        for (int ni = 0; ni < 2; ni++) {
            int gc = ni * 16 + (lane & 15);
#pragma unroll
            for (int j = 0; j < 4; j++) {
                int gr = row0 + wid * 32 + mi * 16 + (lane >> 4) * 4 + j;
                if (gr < N) h2[(size_t)gr * 32 + gc] = acc[mi][ni][j];
            }
        }
}

// as2/ad2 from h2: 8-lane group per node, float4 loads.
__global__ __launch_bounds__(256) void alpha2_kernel(
        const float* __restrict__ h2,
        const float* __restrict__ a_src2, const float* __restrict__ a_dst2,
        float* __restrict__ as2, float* __restrict__ ad2, int N) {
    int t = threadIdx.x;
    int g = t >> 3, q = t & 7;
    int node = blockIdx.x * 32 + g;
    if (node >= N) return;
    float4 v = *(const float4*)&h2[(size_t)node * 32 + q * 4];
    float4 sa = *(const float4*)&a_src2[q * 4];
    float4 da = *(const float4*)&a_dst2[q * 4];
    float s = v.x * sa.x + v.y * sa.y + v.z * sa.z + v.w * sa.w;
    float d = v.x * da.x + v.y * da.y + v.z * da.z + v.w * da.w;
    s += __shfl_xor(s, 1, 8); s += __shfl_xor(s, 2, 8); s += __shfl_xor(s, 4, 8);
    d += __shfl_xor(d, 1, 8); d += __shfl_xor(d, 2, 8); d += __shfl_xor(d, 4, 8);
    if (q == 0) { as2[node] = s; ad2[node] = d; }
}

// Layer-2 per-edge normalized weights. 32-lane group per node (8/block).
__global__ __launch_bounds__(256) void weights2_kernel(
        const float* __restrict__ as2, const float* __restrict__ ad2,
        const int* __restrict__ off, const int* __restrict__ esrc,
        float* __restrict__ alf2, int N) {
    int t = threadIdx.x;
    int g = t >> 5, lane = t & 31;
    int node = blockIdx.x * 8 + g;
    if (node >= N) return;
    int beg = off[node], end = off[node + 1];
    float adv = ad2[node];
    float m = -3.0e38f, dnm = 0.f;
    for (int base = beg; base < end; base += 32) {
        int n_ch = min(32, end - base);
        float ej = -3.0e38f;
        if (lane < n_ch) {
            float e = as2[esrc[base + lane]] + adv;
            ej = (e > 0.f) ? e : 0.2f * e;
        }
        float cm = ej;
#pragma unroll
        for (int s = 16; s > 0; s >>= 1) cm = fmaxf(cm, __shfl_xor(cm, s, 32));
        float nm = fmaxf(m, cm);
        float scl = __expf(m - nm);
        float wj = (lane < n_ch) ? __expf(ej - nm) : 0.f;
        float ws = wj;
#pragma unroll
        for (int s = 16; s > 0; s >>= 1) ws += __shfl_xor(ws, s, 32);
        dnm = dnm * scl + ws;
        m = nm;
    }
    float inv = 1.f / (dnm + 1e-16f);
    for (int base = beg; base < end; base += 32) {
        int n_ch = min(32, end - base);
        if (lane < n_ch) {
            float e = as2[esrc[base + lane]] + adv;
            e = (e > 0.f) ? e : 0.2f * e;
            alf2[base + lane] = __expf(e - m) * inv;
        }
    }
}

// Layer-2 gather-accumulate + bias + log_softmax. 32-lane group per node,
// unrolled x4, weights pre-normalized (no exp, no rescale chain).
__global__ __launch_bounds__(256) void agg2b_kernel(
        const float* __restrict__ h2, const float* __restrict__ alf2,
        const float* __restrict__ b2,
        const int* __restrict__ off, const int* __restrict__ esrc,
        float* __restrict__ out, int N) {
    int t = threadIdx.x;
    int g = t >> 5, c = t & 31;
    int node = blockIdx.x * 8 + g;
    if (node >= N) return;
    int beg = off[node], end = off[node + 1];
    const float* hcol = h2 + c;
    float a0 = 0.f, a1 = 0.f, a2 = 0.f, a3 = 0.f;
    int j = beg;
    for (; j + 4 <= end; j += 4) {
        int s0 = esrc[j + 0], s1 = esrc[j + 1], s2 = esrc[j + 2], s3 = esrc[j + 3];
        float w0 = alf2[j + 0], w1 = alf2[j + 1], w2 = alf2[j + 2], w3 = alf2[j + 3];
        a0 = fmaf(w0, hcol[(size_t)s0 * 32], a0);
        a1 = fmaf(w1, hcol[(size_t)s1 * 32], a1);
        a2 = fmaf(w2, hcol[(size_t)s2 * 32], a2);
        a3 = fmaf(w3, hcol[(size_t)s3 * 32], a3);
    }
    for (; j < end; j++)
        a0 = fmaf(alf2[j], hcol[(size_t)esrc[j] * 32], a0);
    float v = (a0 + a1) + (a2 + a3) + b2[c];
    float mx = v;
#pragma unroll
    for (int s = 16; s > 0; s >>= 1) mx = fmaxf(mx, __shfl_xor(mx, s, 32));
    float sum = __expf(v - mx);
#pragma unroll
    for (int s = 16; s > 0; s >>= 1) sum += __shfl_xor(sum, s, 32);
    out[(size_t)node * 32 + c] = (v - mx) - __logf(sum);
}

extern "C" void kernel_launch(void* const* d_in, const int* in_sizes, int n_in,
                              void* d_out, int out_size, void* d_ws, size_t ws_size,
                              hipStream_t stream) {
    const float* x      = (const float*)d_in[0];
    const void*  ei     = d_in[1];
    const float* W1     = (const float*)d_in[2];
    const float* a_src1 = (const float*)d_in[3];
    const float* a_dst1 = (const float*)d_in[4];
    const float* b1     = (const float*)d_in[5];
    const float* W2     = (const float*)d_in[6];
    const float* a_src2 = (const float*)d_in[7];
    const float* a_dst2 = (const float*)d_in[8];
    const float* b2     = (const float*)d_in[9];
    const int N  = in_sizes[0] / 256;   // 50000
    const int E  = in_sizes[1] / 2;     // 500000
    const int ET = E + N;
    float* outp = (float*)d_out;
    (void)n_in; (void)out_size; (void)ws_size;

    char* ws = (char*)d_ws;
    size_t o = 0;
    auto alloc = [&](size_t bytes) -> void* {
        void* p = ws + o;
        o += (bytes + 255) & ~(size_t)255;
        return p;
    };
    int*    flag   = (int*)alloc(4);
    int*    src32  = (int*)alloc((size_t)ET * 4);
    int*    dst32  = (int*)alloc((size_t)ET * 4);
    int*    deg    = (int*)alloc((size_t)2 * N * 4);
    int*    cursor = deg + N;
    int*    off    = (int*)alloc((size_t)(N + 1) * 4);
    int*    esrc   = (int*)alloc((size_t)ET * 4);
    int*    bsum   = (int*)alloc((size_t)1024 * 4);
    ushort* xb     = (ushort*)alloc((size_t)N * 256 * 2);
    ushort* w1t    = (ushort*)alloc((size_t)256 * 256 * 2);
    ushort* w2t    = (ushort*)alloc((size_t)32 * 256 * 2);
    ushort* h1b    = (ushort*)alloc((size_t)N * 256 * 2);
    float*  as1    = (float*)alloc((size_t)N * 8 * 4);
    float*  ad1    = (float*)alloc((size_t)N * 8 * 4);
    float*  alf1   = (float*)alloc((size_t)ET * 8 * 4);
    ushort* hactb  = (ushort*)alloc((size_t)N * 256 * 2);
    float*  h2     = (float*)alloc((size_t)N * 32 * 4);
    float*  as2    = (float*)alloc((size_t)N * 4);
    float*  ad2    = (float*)alloc((size_t)N * 4);
    float*  alf2   = (float*)alloc((size_t)ET * 4);

    const int nbScan = (N + 255) / 256;   // 196

    zero_kernel<<<(2 * N + 255) / 256, 256, 0, stream>>>(deg, 2 * N);
    detect_kernel<<<1, 256, 0, stream>>>((const int*)ei, flag);
    decode_degree_kernel<<<(ET + 255) / 256, 256, 0, stream>>>(ei, E, ET, N, flag,
                                                               src32, dst32, deg);
    scanA_kernel<<<nbScan, 256, 0, stream>>>(deg, bsum, N);
    scanB_kernel<<<1, 1024, 0, stream>>>(bsum, nbScan);
    scanC_kernel<<<nbScan, 256, 0, stream>>>(deg, bsum, off, N);
    scatter_kernel<<<(ET + 255) / 256, 256, 0, stream>>>(src32, dst32, ET, off,
                                                         cursor, esrc);

    long nx = (long)N * 256;
    convert_x<<<(int)((nx / 8 + 255) / 256), 256, 0, stream>>>(x, xb, nx);
    convert_w1t<<<dim3(8, 8), 256, 0, stream>>>(W1, w1t);
    convert_w2t<<<32, 256, 0, stream>>>(W2, w2t);

    gemm1_mfma<<<dim3((N + 127) / 128, 2), 256, 0, stream>>>(xb, w1t, h1b, N);
    alpha1_kernel<<<(N + 7) / 8, 256, 0, stream>>>(h1b, a_src1, a_dst1, as1, ad1, N);
    weights1_kernel<<<N, 256, 0, stream>>>(as1, ad1, off, esrc, alf1, N);
    agg1b_kernel<<<(N + 3) / 4, 256, 0, stream>>>(h1b, alf1, b1, off, esrc, hactb, N);
    gemm2_mfma<<<(N + 127) / 128, 256, 0, stream>>>(hactb, w2t, h2, N);
    alpha2_kernel<<<(N + 31) / 32, 256, 0, stream>>>(h2, a_src2, a_dst2, as2, ad2, N);
    weights2_kernel<<<(N + 7) / 8, 256, 0, stream>>>(as2, ad2, off, esrc, alf2, N);
    agg2b_kernel<<<(N + 7) / 8, 256, 0, stream>>>(h2, alf2, b2, off, esrc, outp, N);
}

// Round 8
// 225.014 us; speedup vs baseline: 2.3491x; 1.1210x over previous
//
#include <hip/hip_runtime.h>
#include <math.h>

// ---------------------------------------------------------------------------
// GAT 2-layer forward (N=50000, F_in=256, H1=8, C1=32, C2=32, E=500000).
// R7: weights1 transposed to one-thread-per-(node,head) serial 3-pass softmax
// (was: block-per-node with 8 redundant head-groups + shuffle machinery for
// avg-degree-11 rows). 32x fewer threads, zero shuffles/barriers, as1 L2-hot.
// Everything else unchanged from R6.
// ---------------------------------------------------------------------------

typedef __attribute__((ext_vector_type(8))) short bf16x8;
typedef __attribute__((ext_vector_type(4))) float f32x4;

__device__ __forceinline__ float bf2f(ushort u) {
    union { uint i; float f; } v; v.i = ((uint)u) << 16; return v.f;
}
__device__ __forceinline__ ushort f2bf(float f) {  // round-to-nearest-even
    union { float f; uint i; } v; v.f = f;
    uint r = v.i + 0x7FFFu + ((v.i >> 16) & 1u);
    return (ushort)(r >> 16);
}

__global__ void zero_kernel(int* p, int n) {
    int i = blockIdx.x * blockDim.x + threadIdx.x;
    if (i < n) p[i] = 0;
}

// int64 little-endian values < 2^31 => every odd 32-bit word is 0.
__global__ void detect_kernel(const int* ei32, int* flag) {
    __shared__ int cnt;
    if (threadIdx.x == 0) cnt = 0;
    __syncthreads();
    int nz = 0;
    for (int i = threadIdx.x; i < 1024; i += blockDim.x)
        if (ei32[2 * i + 1] != 0) nz++;
    atomicAdd(&cnt, nz);
    __syncthreads();
    if (threadIdx.x == 0) *flag = (cnt > 16) ? 1 : 0;  // 1 => int32 layout
}

__global__ void decode_degree_kernel(const void* ei, int E, int ET, int N,
                                     const int* __restrict__ flag,
                                     int* __restrict__ src, int* __restrict__ dst,
                                     int* __restrict__ deg) {
    int k = blockIdx.x * blockDim.x + threadIdx.x;
    if (k >= ET) return;
    int s, d;
    if (k < E) {
        if (*flag) {
            const int* p = (const int*)ei;
            s = p[k]; d = p[E + k];
        } else {
            const long long* p = (const long long*)ei;
            s = (int)p[k]; d = (int)p[E + k];
        }
    } else {
        s = d = k - E;  // self-loops appended
    }
    s = min(max(s, 0), N - 1);
    d = min(max(d, 0), N - 1);
    src[k] = s; dst[k] = d;
    atomicAdd(&deg[d], 1);
}

// --- 3-phase hierarchical exclusive scan (coalesced, parallel) -------------
__global__ __launch_bounds__(256) void scanA_kernel(const int* __restrict__ deg,
                                                    int* __restrict__ bsum, int n) {
    int i = blockIdx.x * 256 + threadIdx.x;
    int v = (i < n) ? deg[i] : 0;
#pragma unroll
    for (int s = 1; s < 64; s <<= 1) v += __shfl_xor(v, s, 64);
    __shared__ int ws[4];
    int lane = threadIdx.x & 63, wid = threadIdx.x >> 6;
    if (lane == 0) ws[wid] = v;
    __syncthreads();
    if (threadIdx.x == 0) bsum[blockIdx.x] = ws[0] + ws[1] + ws[2] + ws[3];
}

__global__ __launch_bounds__(1024) void scanB_kernel(int* __restrict__ bsum, int nb) {
    int t = threadIdx.x;
    int v = (t < nb) ? bsum[t] : 0;
    __shared__ int sm[1024];
    sm[t] = v;
    __syncthreads();
    for (int s = 1; s < 1024; s <<= 1) {
        int a = (t >= s) ? sm[t - s] : 0;
        __syncthreads();
        sm[t] += a;
        __syncthreads();
    }
    if (t < nb) bsum[t] = sm[t] - v;  // exclusive
}

__global__ __launch_bounds__(256) void scanC_kernel(const int* __restrict__ deg,
                                                    const int* __restrict__ bsum,
                                                    int* __restrict__ off, int n) {
    int t = threadIdx.x;
    int i = blockIdx.x * 256 + t;
    int v = (i < n) ? deg[i] : 0;
    int incl = v;
    int lane = t & 63, wid = t >> 6;
#pragma unroll
    for (int s = 1; s < 64; s <<= 1) {
        int a = __shfl_up(incl, s, 64);
        if (lane >= s) incl += a;
    }
    __shared__ int wsum[4];
    if (lane == 63) wsum[wid] = incl;
    __syncthreads();
    int wo = 0;
    for (int w = 0; w < wid; w++) wo += wsum[w];
    if (i < n) off[i + 1] = bsum[blockIdx.x] + wo + incl;
    if (i == 0) off[0] = 0;
}

__global__ void scatter_kernel(const int* __restrict__ src, const int* __restrict__ dst,
                               int ET, const int* __restrict__ off,
                               int* __restrict__ cursor, int* __restrict__ esrc) {
    int k = blockIdx.x * blockDim.x + threadIdx.x;
    if (k >= ET) return;
    int d = dst[k];
    int p = atomicAdd(&cursor[d], 1);
    esrc[off[d] + p] = src[k];
}

// x fp32 -> bf16, 8 elems/thread.
__global__ void convert_x(const float* __restrict__ x, ushort* __restrict__ xb, long n) {
    long i = ((long)blockIdx.x * blockDim.x + threadIdx.x) * 8;
    if (i >= n) return;
    float4 a = *(const float4*)&x[i];
    float4 b = *(const float4*)&x[i + 4];
    uint4 o;
    o.x = (uint)f2bf(a.x) | ((uint)f2bf(a.y) << 16);
    o.y = (uint)f2bf(a.z) | ((uint)f2bf(a.w) << 16);
    o.z = (uint)f2bf(b.x) | ((uint)f2bf(b.y) << 16);
    o.w = (uint)f2bf(b.z) | ((uint)f2bf(b.w) << 16);
    *(uint4*)&xb[i] = o;
}

// W1[256][256] fp32 -> w1t[256][256] bf16 transposed (w1t[n][k] = W1[k][n]).
__global__ __launch_bounds__(256) void convert_w1t(const float* __restrict__ W1,
                                                   ushort* __restrict__ w1t) {
    __shared__ float tile[32][33];
    int tx = threadIdx.x & 31, ty = threadIdx.x >> 5;
    int bx = blockIdx.x, by = blockIdx.y;
    for (int i = 0; i < 32; i += 8)
        tile[ty + i][tx] = W1[(by * 32 + ty + i) * 256 + bx * 32 + tx];
    __syncthreads();
    for (int i = 0; i < 32; i += 8)
        w1t[(bx * 32 + ty + i) * 256 + by * 32 + tx] = f2bf(tile[tx][ty + i]);
}

// W2[256][32] fp32 -> w2t[32][256] bf16 transposed (w2t[c][k] = W2[k][c]).
__global__ __launch_bounds__(256) void convert_w2t(const float* __restrict__ W2,
                                                   ushort* __restrict__ w2t) {
    int idx = blockIdx.x * 256 + threadIdx.x;   // 32 blocks x 256 = 8192
    int c = idx >> 8, k = idx & 255;
    w2t[idx] = f2bf(W2[k * 32 + c]);
}

// h1 = x @ W1 via bf16 MFMA. 128x128 tile, BK=64, 4 waves (2x2), 4x4 frags.
#define LDA 72
__global__ __launch_bounds__(256) void gemm1_mfma(
        const ushort* __restrict__ xb,    // [N][256] bf16
        const ushort* __restrict__ w1t,   // [256][256] bf16 (n-major)
        ushort* __restrict__ h1b,         // [N][256] bf16 out
        int N) {
    __shared__ ushort Al[128 * LDA];
    __shared__ ushort Bl[128 * LDA];
    int t = threadIdx.x;
    int row0 = blockIdx.x * 128;
    int n0 = blockIdx.y * 128;
    int lane = t & 63, wid = t >> 6;
    int wr = wid >> 1, wc = wid & 1;

    f32x4 acc[4][4] = {};

    int sr = t >> 1, scs = (t & 1) * 32;
    for (int k0 = 0; k0 < 256; k0 += 64) {
        {
            int gr = row0 + sr;
            uint4 v0 = {0,0,0,0}, v1 = {0,0,0,0}, v2 = {0,0,0,0}, v3 = {0,0,0,0};
            if (gr < N) {
                const uint4* g = (const uint4*)(xb + (size_t)gr * 256 + k0 + scs);
                v0 = g[0]; v1 = g[1]; v2 = g[2]; v3 = g[3];
            }
            uint4* d = (uint4*)&Al[sr * LDA + scs];
            d[0] = v0; d[1] = v1; d[2] = v2; d[3] = v3;
        }
        {
            const uint4* g = (const uint4*)(w1t + (size_t)(n0 + sr) * 256 + k0 + scs);
            uint4* d = (uint4*)&Bl[sr * LDA + scs];
            d[0] = g[0]; d[1] = g[1]; d[2] = g[2]; d[3] = g[3];
        }
        __syncthreads();

#pragma unroll
        for (int ks = 0; ks < 2; ks++) {
            int kk = ks * 32 + (lane >> 4) * 8;
            bf16x8 af[4], bfr[4];
#pragma unroll
            for (int mi = 0; mi < 4; mi++) {
                int r = wr * 64 + mi * 16 + (lane & 15);
                af[mi] = *(const bf16x8*)&Al[r * LDA + kk];
            }
#pragma unroll
            for (int ni = 0; ni < 4; ni++) {
                int r = wc * 64 + ni * 16 + (lane & 15);
                bfr[ni] = *(const bf16x8*)&Bl[r * LDA + kk];
            }
#pragma unroll
            for (int mi = 0; mi < 4; mi++)
#pragma unroll
                for (int ni = 0; ni < 4; ni++)
                    acc[mi][ni] = __builtin_amdgcn_mfma_f32_16x16x32_bf16(
                        af[mi], bfr[ni], acc[mi][ni], 0, 0, 0);
        }
        __syncthreads();
    }

    // C/D layout (m89/m91): col = lane&15, row = (lane>>4)*4 + j
#pragma unroll
    for (int mi = 0; mi < 4; mi++)
#pragma unroll
        for (int ni = 0; ni < 4; ni++) {
            int gc = n0 + wc * 64 + ni * 16 + (lane & 15);
#pragma unroll
            for (int j = 0; j < 4; j++) {
                int gr = row0 + wr * 64 + mi * 16 + (lane >> 4) * 4 + j;
                if (gr < N) h1b[(size_t)gr * 256 + gc] = f2bf(acc[mi][ni][j]);
            }
        }
}

// as1/ad1 per (node, head) from bf16 h1. 32-lane group per node.
__global__ __launch_bounds__(256) void alpha1_kernel(
        const ushort* __restrict__ h1b,
        const float* __restrict__ a_src1, const float* __restrict__ a_dst1,
        float* __restrict__ as1, float* __restrict__ ad1, int N) {
    int t = threadIdx.x;
    int g = t >> 5, l = t & 31;
    int node = blockIdx.x * 8 + g;
    if (node >= N) return;
    bf16x8 hv = *(const bf16x8*)&h1b[(size_t)node * 256 + l * 8];
    float s = 0.f, d = 0.f;
#pragma unroll
    for (int i = 0; i < 8; i++) {
        float h = bf2f((ushort)hv[i]);
        s = fmaf(h, a_src1[l * 8 + i], s);
        d = fmaf(h, a_dst1[l * 8 + i], d);
    }
    s += __shfl_xor(s, 1); s += __shfl_xor(s, 2);
    d += __shfl_xor(d, 1); d += __shfl_xor(d, 2);
    if ((l & 3) == 0) {
        as1[node * 8 + (l >> 2)] = s;
        ad1[node * 8 + (l >> 2)] = d;
    }
}

// Layer-1 per-edge normalized weights, one THREAD per (node, head):
// exact 3-pass softmax (max / denom / write), serial over the CSR row.
// esrc[j] broadcasts across the node's 8 lanes; as1 (1.6 MB) is L2-hot;
// alf1 writes are 32B-coalesced per edge. No shuffles, no barriers.
__global__ __launch_bounds__(256) void weights1_kernel(
        const float* __restrict__ as1, const float* __restrict__ ad1,
        const int* __restrict__ off, const int* __restrict__ esrc,
        float* __restrict__ alf1, int NH) {
    int tid = blockIdx.x * 256 + threadIdx.x;
    if (tid >= NH) return;
    int node = tid >> 3, head = tid & 7;
    int beg = off[node], end = off[node + 1];
    float adv = ad1[tid];              // ad1[node*8 + head]
    float m = -3.0e38f;
    for (int j = beg; j < end; j++) {
        float e = as1[esrc[j] * 8 + head] + adv;
        e = (e > 0.f) ? e : 0.2f * e;  // leaky_relu(0.2)
        m = fmaxf(m, e);
    }
    float dnm = 0.f;
    for (int j = beg; j < end; j++) {
        float e = as1[esrc[j] * 8 + head] + adv;
        e = (e > 0.f) ? e : 0.2f * e;
        dnm += __expf(e - m);
    }
    float inv = 1.f / (dnm + 1e-16f);
    for (int j = beg; j < end; j++) {
        float e = as1[esrc[j] * 8 + head] + adv;
        e = (e > 0.f) ? e : 0.2f * e;
        alf1[(size_t)j * 8 + head] = __expf(e - m) * inv;
    }
}

// Layer-1 gather-accumulate: one 64-lane wave per node, 4 channels/lane via
// uint2 bf16 loads (512B per wave per edge), edge loop unrolled x4 with
// independent chains. Weights already normalized. Fuses +b1, elu, bf16 store.
__global__ __launch_bounds__(256) void agg1b_kernel(
        const ushort* __restrict__ h1b, const float* __restrict__ alf1,
        const float* __restrict__ b1,
        const int* __restrict__ off, const int* __restrict__ esrc,
        ushort* __restrict__ hactb, int N) {
    int t = threadIdx.x;
    int node = blockIdx.x * 4 + (t >> 6);
    int lane = t & 63;
    if (node >= N) return;
    int beg = off[node], end = off[node + 1];
    int ch0 = lane * 4;
    int head = lane >> 3;              // ch0/32
    const ushort* hb = h1b + ch0;
    const float* af = alf1 + head;
    float c0 = 0.f, c1 = 0.f, c2 = 0.f, c3 = 0.f;
    int j = beg;
    for (; j + 4 <= end; j += 4) {
        int s0 = esrc[j + 0], s1 = esrc[j + 1], s2 = esrc[j + 2], s3 = esrc[j + 3];
        float w0 = af[(size_t)(j + 0) * 8];
        float w1 = af[(size_t)(j + 1) * 8];
        float w2 = af[(size_t)(j + 2) * 8];
        float w3 = af[(size_t)(j + 3) * 8];
        uint2 v0 = *(const uint2*)(hb + (size_t)s0 * 256);
        uint2 v1 = *(const uint2*)(hb + (size_t)s1 * 256);
        uint2 v2 = *(const uint2*)(hb + (size_t)s2 * 256);
        uint2 v3 = *(const uint2*)(hb + (size_t)s3 * 256);
        c0 = fmaf(w0, bf2f((ushort)(v0.x & 0xffffu)), c0);
        c1 = fmaf(w0, bf2f((ushort)(v0.x >> 16)), c1);
        c2 = fmaf(w0, bf2f((ushort)(v0.y & 0xffffu)), c2);
        c3 = fmaf(w0, bf2f((ushort)(v0.y >> 16)), c3);
        c0 = fmaf(w1, bf2f((ushort)(v1.x & 0xffffu)), c0);
        c1 = fmaf(w1, bf2f((ushort)(v1.x >> 16)), c1);
        c2 = fmaf(w1, bf2f((ushort)(v1.y & 0xffffu)), c2);
        c3 = fmaf(w1, bf2f((ushort)(v1.y >> 16)), c3);
        c0 = fmaf(w2, bf2f((ushort)(v2.x & 0xffffu)), c0);
        c1 = fmaf(w2, bf2f((ushort)(v2.x >> 16)), c1);
        c2 = fmaf(w2, bf2f((ushort)(v2.y & 0xffffu)), c2);
        c3 = fmaf(w2, bf2f((ushort)(v2.y >> 16)), c3);
        c0 = fmaf(w3, bf2f((ushort)(v3.x & 0xffffu)), c0);
        c1 = fmaf(w3, bf2f((ushort)(v3.x >> 16)), c1);
        c2 = fmaf(w3, bf2f((ushort)(v3.y & 0xffffu)), c2);
        c3 = fmaf(w3, bf2f((ushort)(v3.y >> 16)), c3);
    }
    for (; j < end; j++) {
        int s0 = esrc[j];
        float w = af[(size_t)j * 8];
        uint2 v = *(const uint2*)(hb + (size_t)s0 * 256);
        c0 = fmaf(w, bf2f((ushort)(v.x & 0xffffu)), c0);
        c1 = fmaf(w, bf2f((ushort)(v.x >> 16)), c1);
        c2 = fmaf(w, bf2f((ushort)(v.y & 0xffffu)), c2);
        c3 = fmaf(w, bf2f((ushort)(v.y >> 16)), c3);
    }
    float4 bv = *(const float4*)&b1[ch0];
    float o0 = c0 + bv.x, o1 = c1 + bv.y, o2 = c2 + bv.z, o3 = c3 + bv.w;
    o0 = (o0 > 0.f) ? o0 : (__expf(o0) - 1.f);
    o1 = (o1 > 0.f) ? o1 : (__expf(o1) - 1.f);
    o2 = (o2 > 0.f) ? o2 : (__expf(o2) - 1.f);
    o3 = (o3 > 0.f) ? o3 : (__expf(o3) - 1.f);
    uint2 r;
    r.x = (uint)f2bf(o0) | ((uint)f2bf(o1) << 16);
    r.y = (uint)f2bf(o2) | ((uint)f2bf(o3) << 16);
    *(uint2*)(hactb + (size_t)node * 256 + ch0) = r;
}

// h2 = hactb @ W2 via bf16 MFMA. Tile 128x32, BK=64, 4 waves each owning a
// 32x32 m-subtile (2x2 frags). Output f32.
__global__ __launch_bounds__(256) void gemm2_mfma(
        const ushort* __restrict__ hactb,  // [N][256] bf16
        const ushort* __restrict__ w2t,    // [32][256] bf16 (c-major)
        float* __restrict__ h2, int N) {
    __shared__ ushort Al[128 * LDA];
    __shared__ ushort Bl[32 * LDA];
    int t = threadIdx.x;
    int row0 = blockIdx.x * 128;
    int lane = t & 63, wid = t >> 6;

    f32x4 acc[2][2] = {};

    int sr = t >> 1, scs = (t & 1) * 32;
    for (int k0 = 0; k0 < 256; k0 += 64) {
        {
            int gr = row0 + sr;
            uint4 v0 = {0,0,0,0}, v1 = {0,0,0,0}, v2 = {0,0,0,0}, v3 = {0,0,0,0};
            if (gr < N) {
                const uint4* g = (const uint4*)(hactb + (size_t)gr * 256 + k0 + scs);
                v0 = g[0]; v1 = g[1]; v2 = g[2]; v3 = g[3];
            }
            uint4* d = (uint4*)&Al[sr * LDA + scs];
            d[0] = v0; d[1] = v1; d[2] = v2; d[3] = v3;
        }
        if (t < 64) {
            const uint4* g = (const uint4*)(w2t + (size_t)sr * 256 + k0 + scs);
            uint4* d = (uint4*)&Bl[sr * LDA + scs];
            d[0] = g[0]; d[1] = g[1]; d[2] = g[2]; d[3] = g[3];
        }
        __syncthreads();

#pragma unroll
        for (int ks = 0; ks < 2; ks++) {
            int kk = ks * 32 + (lane >> 4) * 8;
            bf16x8 af[2], bfr[2];
#pragma unroll
            for (int mi = 0; mi < 2; mi++) {
                int r = wid * 32 + mi * 16 + (lane & 15);
                af[mi] = *(const bf16x8*)&Al[r * LDA + kk];
            }
#pragma unroll
            for (int ni = 0; ni < 2; ni++) {
                int r = ni * 16 + (lane & 15);
                bfr[ni] = *(const bf16x8*)&Bl[r * LDA + kk];
            }
#pragma unroll
            for (int mi = 0; mi < 2; mi++)
#pragma unroll
                for (int ni = 0; ni < 2; ni++)
                    acc[mi][ni] = __builtin_amdgcn_mfma_f32_16x16x32_bf16(
                        af[mi], bfr[ni], acc[mi][ni], 0, 0, 0);
        }
        __syncthreads();
    }

#pragma unroll
    for (int mi = 0; mi < 2; mi++)
#pragma unroll
        for (int ni = 0; ni < 2; ni++) {
            int gc = ni * 16 + (lane & 15);
#pragma unroll
            for (int j = 0; j < 4; j++) {
                int gr = row0 + wid * 32 + mi * 16 + (lane >> 4) * 4 + j;
                if (gr < N) h2[(size_t)gr * 32 + gc] = acc[mi][ni][j];
            }
        }
}

// as2/ad2 from h2: 8-lane group per node, float4 loads.
__global__ __launch_bounds__(256) void alpha2_kernel(
        const float* __restrict__ h2,
        const float* __restrict__ a_src2, const float* __restrict__ a_dst2,
        float* __restrict__ as2, float* __restrict__ ad2, int N) {
    int t = threadIdx.x;
    int g = t >> 3, q = t & 7;
    int node = blockIdx.x * 32 + g;
    if (node >= N) return;
    float4 v = *(const float4*)&h2[(size_t)node * 32 + q * 4];
    float4 sa = *(const float4*)&a_src2[q * 4];
    float4 da = *(const float4*)&a_dst2[q * 4];
    float s = v.x * sa.x + v.y * sa.y + v.z * sa.z + v.w * sa.w;
    float d = v.x * da.x + v.y * da.y + v.z * da.z + v.w * da.w;
    s += __shfl_xor(s, 1, 8); s += __shfl_xor(s, 2, 8); s += __shfl_xor(s, 4, 8);
    d += __shfl_xor(d, 1, 8); d += __shfl_xor(d, 2, 8); d += __shfl_xor(d, 4, 8);
    if (q == 0) { as2[node] = s; ad2[node] = d; }
}

// Layer-2 per-edge normalized weights. 32-lane group per node (8/block).
__global__ __launch_bounds__(256) void weights2_kernel(
        const float* __restrict__ as2, const float* __restrict__ ad2,
        const int* __restrict__ off, const int* __restrict__ esrc,
        float* __restrict__ alf2, int N) {
    int t = threadIdx.x;
    int g = t >> 5, lane = t & 31;
    int node = blockIdx.x * 8 + g;
    if (node >= N) return;
    int beg = off[node], end = off[node + 1];
    float adv = ad2[node];
    float m = -3.0e38f, dnm = 0.f;
    for (int base = beg; base < end; base += 32) {
        int n_ch = min(32, end - base);
        float ej = -3.0e38f;
        if (lane < n_ch) {
            float e = as2[esrc[base + lane]] + adv;
            ej = (e > 0.f) ? e : 0.2f * e;
        }
        float cm = ej;
#pragma unroll
        for (int s = 16; s > 0; s >>= 1) cm = fmaxf(cm, __shfl_xor(cm, s, 32));
        float nm = fmaxf(m, cm);
        float scl = __expf(m - nm);
        float wj = (lane < n_ch) ? __expf(ej - nm) : 0.f;
        float ws = wj;
#pragma unroll
        for (int s = 16; s > 0; s >>= 1) ws += __shfl_xor(ws, s, 32);
        dnm = dnm * scl + ws;
        m = nm;
    }
    float inv = 1.f / (dnm + 1e-16f);
    for (int base = beg; base < end; base += 32) {
        int n_ch = min(32, end - base);
        if (lane < n_ch) {
            float e = as2[esrc[base + lane]] + adv;
            e = (e > 0.f) ? e : 0.2f * e;
            alf2[base + lane] = __expf(e - m) * inv;
        }
    }
}

// Layer-2 gather-accumulate + bias + log_softmax. 32-lane group per node,
// unrolled x4, weights pre-normalized (no exp, no rescale chain).
__global__ __launch_bounds__(256) void agg2b_kernel(
        const float* __restrict__ h2, const float* __restrict__ alf2,
        const float* __restrict__ b2,
        const int* __restrict__ off, const int* __restrict__ esrc,
        float* __restrict__ out, int N) {
    int t = threadIdx.x;
    int g = t >> 5, c = t & 31;
    int node = blockIdx.x * 8 + g;
    if (node >= N) return;
    int beg = off[node], end = off[node + 1];
    const float* hcol = h2 + c;
    float a0 = 0.f, a1 = 0.f, a2 = 0.f, a3 = 0.f;
    int j = beg;
    for (; j + 4 <= end; j += 4) {
        int s0 = esrc[j + 0], s1 = esrc[j + 1], s2 = esrc[j + 2], s3 = esrc[j + 3];
        float w0 = alf2[j + 0], w1 = alf2[j + 1], w2 = alf2[j + 2], w3 = alf2[j + 3];
        a0 = fmaf(w0, hcol[(size_t)s0 * 32], a0);
        a1 = fmaf(w1, hcol[(size_t)s1 * 32], a1);
        a2 = fmaf(w2, hcol[(size_t)s2 * 32], a2);
        a3 = fmaf(w3, hcol[(size_t)s3 * 32], a3);
    }
    for (; j < end; j++)
        a0 = fmaf(alf2[j], hcol[(size_t)esrc[j] * 32], a0);
    float v = (a0 + a1) + (a2 + a3) + b2[c];
    float mx = v;
#pragma unroll
    for (int s = 16; s > 0; s >>= 1) mx = fmaxf(mx, __shfl_xor(mx, s, 32));
    float sum = __expf(v - mx);
#pragma unroll
    for (int s = 16; s > 0; s >>= 1) sum += __shfl_xor(sum, s, 32);
    out[(size_t)node * 32 + c] = (v - mx) - __logf(sum);
}

extern "C" void kernel_launch(void* const* d_in, const int* in_sizes, int n_in,
                              void* d_out, int out_size, void* d_ws, size_t ws_size,
                              hipStream_t stream) {
    const float* x      = (const float*)d_in[0];
    const void*  ei     = d_in[1];
    const float* W1     = (const float*)d_in[2];
    const float* a_src1 = (const float*)d_in[3];
    const float* a_dst1 = (const float*)d_in[4];
    const float* b1     = (const float*)d_in[5];
    const float* W2     = (const float*)d_in[6];
    const float* a_src2 = (const float*)d_in[7];
    const float* a_dst2 = (const float*)d_in[8];
    const float* b2     = (const float*)d_in[9];
    const int N  = in_sizes[0] / 256;   // 50000
    const int E  = in_sizes[1] / 2;     // 500000
    const int ET = E + N;
    float* outp = (float*)d_out;
    (void)n_in; (void)out_size; (void)ws_size;

    char* ws = (char*)d_ws;
    size_t o = 0;
    auto alloc = [&](size_t bytes) -> void* {
        void* p = ws + o;
        o += (bytes + 255) & ~(size_t)255;
        return p;
    };
    int*    flag   = (int*)alloc(4);
    int*    src32  = (int*)alloc((size_t)ET * 4);
    int*    dst32  = (int*)alloc((size_t)ET * 4);
    int*    deg    = (int*)alloc((size_t)2 * N * 4);
    int*    cursor = deg + N;
    int*    off    = (int*)alloc((size_t)(N + 1) * 4);
    int*    esrc   = (int*)alloc((size_t)ET * 4);
    int*    bsum   = (int*)alloc((size_t)1024 * 4);
    ushort* xb     = (ushort*)alloc((size_t)N * 256 * 2);
    ushort* w1t    = (ushort*)alloc((size_t)256 * 256 * 2);
    ushort* w2t    = (ushort*)alloc((size_t)32 * 256 * 2);
    ushort* h1b    = (ushort*)alloc((size_t)N * 256 * 2);
    float*  as1    = (float*)alloc((size_t)N * 8 * 4);
    float*  ad1    = (float*)alloc((size_t)N * 8 * 4);
    float*  alf1   = (float*)alloc((size_t)ET * 8 * 4);
    ushort* hactb  = (ushort*)alloc((size_t)N * 256 * 2);
    float*  h2     = (float*)alloc((size_t)N * 32 * 4);
    float*  as2    = (float*)alloc((size_t)N * 4);
    float*  ad2    = (float*)alloc((size_t)N * 4);
    float*  alf2   = (float*)alloc((size_t)ET * 4);

    const int nbScan = (N + 255) / 256;   // 196

    zero_kernel<<<(2 * N + 255) / 256, 256, 0, stream>>>(deg, 2 * N);
    detect_kernel<<<1, 256, 0, stream>>>((const int*)ei, flag);
    decode_degree_kernel<<<(ET + 255) / 256, 256, 0, stream>>>(ei, E, ET, N, flag,
                                                               src32, dst32, deg);
    scanA_kernel<<<nbScan, 256, 0, stream>>>(deg, bsum, N);
    scanB_kernel<<<1, 1024, 0, stream>>>(bsum, nbScan);
    scanC_kernel<<<nbScan, 256, 0, stream>>>(deg, bsum, off, N);
    scatter_kernel<<<(ET + 255) / 256, 256, 0, stream>>>(src32, dst32, ET, off,
                                                         cursor, esrc);

    long nx = (long)N * 256;
    convert_x<<<(int)((nx / 8 + 255) / 256), 256, 0, stream>>>(x, xb, nx);
    convert_w1t<<<dim3(8, 8), 256, 0, stream>>>(W1, w1t);
    convert_w2t<<<32, 256, 0, stream>>>(W2, w2t);

    gemm1_mfma<<<dim3((N + 127) / 128, 2), 256, 0, stream>>>(xb, w1t, h1b, N);
    alpha1_kernel<<<(N + 7) / 8, 256, 0, stream>>>(h1b, a_src1, a_dst1, as1, ad1, N);
    weights1_kernel<<<(N * 8 + 255) / 256, 256, 0, stream>>>(as1, ad1, off, esrc,
                                                             alf1, N * 8);
    agg1b_kernel<<<(N + 3) / 4, 256, 0, stream>>>(h1b, alf1, b1, off, esrc, hactb, N);
    gemm2_mfma<<<(N + 127) / 128, 256, 0, stream>>>(hactb, w2t, h2, N);
    alpha2_kernel<<<(N + 31) / 32, 256, 0, stream>>>(h2, a_src2, a_dst2, as2, ad2, N);
    weights2_kernel<<<(N + 7) / 8, 256, 0, stream>>>(as2, ad2, off, esrc, alf2, N);
    agg2b_kernel<<<(N + 7) / 8, 256, 0, stream>>>(h2, alf2, b2, off, esrc, outp, N);
}